// Round 8
// baseline (1417.260 us; speedup 1.0000x reference)
//
#include <hip/hip_runtime.h>

typedef __bf16 bf16;
typedef __attribute__((ext_vector_type(8))) __bf16 bf16x8;
typedef __attribute__((ext_vector_type(4))) __bf16 bf16x4;
typedef __attribute__((ext_vector_type(4))) float f32x4;

#define GL16(gp, lp) __builtin_amdgcn_global_load_lds( \
    (const __attribute__((address_space(1))) unsigned int*)(gp), \
    (__attribute__((address_space(3))) unsigned int*)(lp), 16, 0, 0)

__device__ __forceinline__ f32x4 mfma16(bf16x8 a, bf16x8 b, f32x4 c) {
  return __builtin_amdgcn_mfma_f32_16x16x32_bf16(a, b, c, 0, 0, 0);
}

// ---------------------------------------------------------------------------
// Generic bf16 GEMM: C[M][N] = A[M][K] (bf16, row-major) * Bt[N][K]^T (bf16)
// BM=128 x BN tile, BK=32, 4 waves. BN=128: 2x2 waves of 64x64 (0.5 LDS
// reads/MFMA). BN=64: 2x2 waves of 64x32 (0.75 reads/MFMA, grid 2x larger:
// 2-4 blocks/CU for N<=1024 shapes). 3 LDS buffers, 2-deep prefetch,
// counted vmcnt. Chunk-XOR LDS swizzle (both-sides) -> 0 bank conflicts.
// XCD-aware block swizzle. Optional bias (fp32), residual (bf16), ReLU.
// ---------------------------------------------------------------------------
template<int BN, int RELU, int BIAS, int RES, int OUTB>
__global__ __launch_bounds__(256, 2) void gemm_k(
    const bf16* __restrict__ A, const bf16* __restrict__ Bt,
    float* __restrict__ Cf, bf16* __restrict__ Cb,
    const float* __restrict__ bias, const bf16* __restrict__ resid,
    int M, int N, int K)
{
  constexpr int MI = 4;             // 128 M rows / 16 / 2 wave-rows
  constexpr int NI = BN / 32;       // 4 (BN=128) or 2 (BN=64)
  __shared__ __align__(16) bf16 Al[3][128 * 32];
  __shared__ __align__(16) bf16 Bl[3][BN * 32];
  const int tid = threadIdx.x;
  const int wid = tid >> 6, lane = tid & 63;
  const int g = lane >> 4, l16 = lane & 15;

  // XCD swizzle: HW assigns XCD = lin%8; give each XCD a contiguous tile range
  int lin = blockIdx.x + gridDim.x * blockIdx.y;
  const int nwg = gridDim.x * gridDim.y;
  if ((nwg & 7) == 0) lin = (lin & 7) * (nwg >> 3) + (lin >> 3);
  const int bx = lin % gridDim.x, by = lin / gridDim.x;

  const int bm = by * 128, bn = bx * BN;
  const int wm = (wid >> 1) * 64;           // wave rows: 64
  const int wn = (wid & 1) * (BN / 2);      // wave cols: 64 or 32

  const f32x4 z4 = {0.f, 0.f, 0.f, 0.f};
  f32x4 acc[MI][NI];
#pragma unroll
  for (int i = 0; i < MI; ++i)
#pragma unroll
    for (int j = 0; j < NI; ++j) acc[i][j] = z4;

  // staging: srow = tid>>2 (0..63), chunk = tid&3; source col pre-swizzled
  const int srow = tid >> 2;
  const int scs = (((tid & 3) ^ ((srow >> 1) & 3)) * 8);   // swizzled col elems
  const bf16* Ag = A + (size_t)(bm + srow) * K + scs;
  const bf16* Bg = Bt + (size_t)(bn + srow) * K + scs;
  const size_t half = (size_t)64 * K;

  auto stage = [&](int sel, int k0) {
    GL16(Ag + k0, &Al[sel][tid * 8]);
    GL16(Ag + k0 + half, &Al[sel][2048 + tid * 8]);
    GL16(Bg + k0, &Bl[sel][tid * 8]);
    if constexpr (BN == 128) GL16(Bg + k0 + half, &Bl[sel][2048 + tid * 8]);
  };
  constexpr int NL = 2 + BN / 64;   // loads per wave per stage (3 or 4)

  const int nsteps = K >> 5;
  stage(0, 0);
  stage(1, 32);
  int cur = 0;
  for (int s = 0; s < nsteps; ++s) {
    __builtin_amdgcn_sched_barrier(0);
    if (s + 1 < nsteps) {
      if constexpr (NL == 4)
        asm volatile("s_waitcnt vmcnt(4)" ::: "memory");
      else
        asm volatile("s_waitcnt vmcnt(3)" ::: "memory");
    } else {
      asm volatile("s_waitcnt vmcnt(0)" ::: "memory");
    }
    __builtin_amdgcn_sched_barrier(0);
    __builtin_amdgcn_s_barrier();
    if (s + 2 < nsteps) {
      int pre = cur + 2; if (pre >= 3) pre -= 3;
      stage(pre, (s + 2) * 32);   // 2-deep prefetch into the idle buffer
    }
    bf16x8 af[MI], bfr[NI];
#pragma unroll
    for (int mi = 0; mi < MI; ++mi) {
      const int row = wm + mi * 16 + l16;
      af[mi] = *(const bf16x8*)&Al[cur][row * 32 + (g ^ ((row >> 1) & 3)) * 8];
    }
#pragma unroll
    for (int ni = 0; ni < NI; ++ni) {
      const int row = wn + ni * 16 + l16;
      bfr[ni] = *(const bf16x8*)&Bl[cur][row * 32 + (g ^ ((row >> 1) & 3)) * 8];
    }
#pragma unroll
    for (int mi = 0; mi < MI; ++mi)
#pragma unroll
      for (int ni = 0; ni < NI; ++ni)
        acc[mi][ni] = mfma16(af[mi], bfr[ni], acc[mi][ni]);
    ++cur; if (cur >= 3) cur = 0;
  }

#pragma unroll
  for (int mi = 0; mi < MI; ++mi) {
#pragma unroll
    for (int ni = 0; ni < NI; ++ni) {
#pragma unroll
      for (int r = 0; r < 4; ++r) {
        const int row = bm + wm + mi * 16 + g * 4 + r;
        const int col = bn + wn + ni * 16 + l16;
        float v = acc[mi][ni][r];
        if (BIAS) v += bias[col];
        const size_t idx = (size_t)row * N + col;
        if (RES)  v += (float)resid[idx];
        if (RELU) v = fmaxf(v, 0.f);
        if (OUTB) Cb[idx] = (bf16)v;
        else      Cf[idx] = v;
      }
    }
  }
}

// ---------------------------------------------------------------------------
// Flash attention, MFMA. One block = (b, h, 64-row q tile), 4 waves x 16 q
// rows. KV tiles of 64, double-buffered + 1-deep prefetch. K/V^T staged via
// global_load_lds (linear dest) with XOR-swizzled global source column;
// ds_read_b128 fragment reads conflict-free. V^T precomputed:
// VT [b*8+h][64 dh][512 t]. P per-wave in LDS, same swizzle.
// XCD swizzle: 8 q-tile blocks of one (b,h) colocate -> K/V L2 reuse.
// ---------------------------------------------------------------------------
template<int CAUSAL>
__global__ __launch_bounds__(256, 4) void attn_k(
    const bf16* __restrict__ Q, const bf16* __restrict__ Kg,
    const bf16* __restrict__ VT, bf16* __restrict__ O, int qs, int kvs)
{
  __shared__ __align__(16) bf16 Kl[2][64 * 64];
  __shared__ __align__(16) bf16 Vl[2][64 * 64];
  __shared__ __align__(16) bf16 plb[4 * 16 * 64];
  const int tid = threadIdx.x;
  const int wid = tid >> 6, lane = tid & 63;
  const int g = lane >> 4, l16 = lane & 15;

  // grid (8,8,16) flattened; XCD swizzle (nwg=1024, q=128)
  int lin = blockIdx.x + 8 * blockIdx.y + 64 * blockIdx.z;
  lin = (lin & 7) * 128 + (lin >> 3);
  const int qt = lin & 7, h = (lin >> 3) & 7, b = lin >> 6;

  const int q0 = qt * 64 + wid * 16;
  const size_t tokQ = (size_t)b * 512 + q0;

  const bf16* qp = Q + (tokQ + l16) * (size_t)qs + h * 64 + g * 8;
  const bf16x8 qf0 = *(const bf16x8*)qp;
  const bf16x8 qf1 = *(const bf16x8*)(qp + 32);

  // staging source: row sr = tid>>3, swizzled col (both-sides pattern)
  const int sr = tid >> 3;
  const int cs2 = ((((tid & 7) * 16) ^ ((sr & 7) << 4)) >> 1);  // bf16 elems
  const bf16* Ksrc = Kg + ((size_t)b * 512 + sr) * kvs + h * 64 + cs2;
  const bf16* Vsrc = VT + (size_t)(b * 8 + h) * 64 * 512 + (size_t)sr * 512 + cs2;
  bf16* pw = plb + wid * 1024;

  auto stage = [&](int sel, int t0) {
    GL16(Ksrc + (size_t)t0 * kvs, &Kl[sel][tid * 8]);
    GL16(Ksrc + (size_t)(t0 + 32) * kvs, &Kl[sel][tid * 8 + 2048]);
    GL16(Vsrc + t0, &Vl[sel][tid * 8]);
    GL16(Vsrc + 32 * 512 + t0, &Vl[sel][tid * 8 + 2048]);
  };

  const f32x4 z4 = {0.f, 0.f, 0.f, 0.f};
  float m[4], ls[4];
  f32x4 o[4];
#pragma unroll
  for (int r = 0; r < 4; ++r) { m[r] = -1e30f; ls[r] = 0.f; o[r] = z4; }

  const int sw = (l16 & 7) << 4;   // byte swizzle for fragment reads
  const int ktmax = CAUSAL ? qt : 7;
  stage(0, 0);
  int cur = 0;
  for (int kt = 0; kt <= ktmax; ++kt) {
    const int t0 = kt * 64;
    __builtin_amdgcn_sched_barrier(0);
    asm volatile("s_waitcnt vmcnt(0)" ::: "memory");
    __builtin_amdgcn_s_barrier();
    if (kt < ktmax) stage(cur ^ 1, t0 + 64);    // prefetch next KV tile

    // QK^T -> 4 16x16 tiles per wave (t cols t0 + jt*16 + l16)
    f32x4 sc[4];
#pragma unroll
    for (int jt = 0; jt < 4; ++jt) {
      const int rk = jt * 16 + l16;
      const bf16x8 kf0 = *(const bf16x8*)&Kl[cur][rk * 64 + (((g * 16) ^ sw) >> 1)];
      const bf16x8 kf1 = *(const bf16x8*)&Kl[cur][rk * 64 + (((g * 16 + 64) ^ sw) >> 1)];
      sc[jt] = mfma16(qf0, kf0, z4);
      sc[jt] = mfma16(qf1, kf1, sc[jt]);
    }
    // online softmax per row r (row q = g*4+r, col = jt*16+l16)
#pragma unroll
    for (int r = 0; r < 4; ++r) {
      const int q = g * 4 + r;
      const int srow = q0 + q;
      const int qs7 = (q & 7) << 4;
      float pv[4];
      float mx = -1e30f;
#pragma unroll
      for (int jt = 0; jt < 4; ++jt) {
        float v = sc[jt][r] * 0.125f;   // 1/sqrt(64)
        if (CAUSAL && (t0 + jt * 16 + l16) > srow) v = -1e30f;
        pv[jt] = v;
        mx = fmaxf(mx, v);
      }
#pragma unroll
      for (int msk = 8; msk; msk >>= 1) mx = fmaxf(mx, __shfl_xor(mx, msk));
      const float mn = fmaxf(m[r], mx);
      const float corr = __expf(m[r] - mn);
      float s = 0.f;
#pragma unroll
      for (int jt = 0; jt < 4; ++jt) {
        const float p = __expf(pv[jt] - mn);
        s += p;
        const int sb = (((jt * 16 + l16) * 2) ^ qs7) >> 1;
        pw[q * 64 + sb] = (bf16)p;
      }
#pragma unroll
      for (int msk = 8; msk; msk >>= 1) s += __shfl_xor(s, msk);
      ls[r] = ls[r] * corr + s;
      m[r] = mn;
#pragma unroll
      for (int j = 0; j < 4; ++j) o[j][r] *= corr;
    }
    // same-wave LDS visibility for P (no cross-wave sharing of P)
    asm volatile("s_waitcnt lgkmcnt(0)" ::: "memory");
    __builtin_amdgcn_sched_barrier(0);
    const bf16x8 pa0 = *(const bf16x8*)&pw[l16 * 64 + (((g * 16) ^ sw) >> 1)];
    const bf16x8 pa1 = *(const bf16x8*)&pw[l16 * 64 + (((g * 16 + 64) ^ sw) >> 1)];
#pragma unroll
    for (int j = 0; j < 4; ++j) {
      const int rv = j * 16 + l16;
      const bf16x8 vf0 = *(const bf16x8*)&Vl[cur][rv * 64 + (((g * 16) ^ sw) >> 1)];
      const bf16x8 vf1 = *(const bf16x8*)&Vl[cur][rv * 64 + (((g * 16 + 64) ^ sw) >> 1)];
      o[j] = mfma16(pa0, vf0, o[j]);
      o[j] = mfma16(pa1, vf1, o[j]);
    }
    cur ^= 1;
  }
#pragma unroll
  for (int r = 0; r < 4; ++r) {
    const float inv = 1.f / ls[r];
    bf16* op = O + (tokQ + g * 4 + r) * 512 + h * 64;
#pragma unroll
    for (int j = 0; j < 4; ++j) op[j * 16 + l16] = (bf16)(o[j][r] * inv);
  }
}

// ---------------------------------------------------------------------------
// V^T precompute: src = V rows [t][dh] (row stride `stride`), dst =
// VT [b*8+h][64 dh][512 t]. Grid (8 t-tiles, 1, 128 bh), block (64,4).
// ---------------------------------------------------------------------------
__global__ void vtrans(const bf16* __restrict__ src, bf16* __restrict__ dst,
                       int stride)
{
  __shared__ bf16 t[64][65];
  const int bh = blockIdx.z;
  const int b = bh >> 3, h = bh & 7;
  const int t0 = blockIdx.x * 64;
  const int tx = threadIdx.x, ty = threadIdx.y;
  src += ((size_t)b * 512 + t0) * stride + h * 64;
  dst += (size_t)bh * 64 * 512 + t0;
#pragma unroll
  for (int j = 0; j < 64; j += 4)
    t[ty + j][tx] = src[(size_t)(ty + j) * stride + tx];
  __syncthreads();
#pragma unroll
  for (int j = 0; j < 64; j += 4)
    dst[(size_t)(ty + j) * 512 + tx] = t[tx][ty + j];
}

// ---------------------------------------------------------------------------
// LayerNorm over D=512. One wave per row; fp32 math; writes bf16 and/or fp32.
// ---------------------------------------------------------------------------
__global__ __launch_bounds__(256) void ln_k(
    const float* __restrict__ z, const float* __restrict__ gam,
    const float* __restrict__ bet, float* __restrict__ of,
    bf16* __restrict__ ob)
{
  const int wid = threadIdx.x >> 6, lane = threadIdx.x & 63;
  const int row = blockIdx.x * 4 + wid;
  const f32x4* zr = (const f32x4*)(z + (size_t)row * 512);
  const f32x4 a = zr[lane], c = zr[lane + 64];
  float s = 0.f, ss = 0.f;
#pragma unroll
  for (int e = 0; e < 4; ++e) {
    s += a[e] + c[e];
    ss += a[e] * a[e] + c[e] * c[e];
  }
#pragma unroll
  for (int msk = 32; msk; msk >>= 1) {
    s += __shfl_xor(s, msk);
    ss += __shfl_xor(ss, msk);
  }
  const float mean = s * (1.f / 512.f);
  const float var = ss * (1.f / 512.f) - mean * mean;
  const float rstd = rsqrtf(var + 1e-5f);
  const f32x4* gp = (const f32x4*)gam;
  const f32x4* bp = (const f32x4*)bet;
  const f32x4 g0 = gp[lane], g1 = gp[lane + 64];
  const f32x4 b0 = bp[lane], b1 = bp[lane + 64];
  f32x4 o0, o1;
#pragma unroll
  for (int e = 0; e < 4; ++e) {
    o0[e] = (a[e] - mean) * rstd * g0[e] + b0[e];
    o1[e] = (c[e] - mean) * rstd * g1[e] + b1[e];
  }
  if (of) {
    f32x4* ofr = (f32x4*)(of + (size_t)row * 512);
    ofr[lane] = o0;
    ofr[lane + 64] = o1;
  }
  if (ob) {
    bf16x4 c0, c1;
#pragma unroll
    for (int e = 0; e < 4; ++e) { c0[e] = (bf16)o0[e]; c1[e] = (bf16)o1[e]; }
    bf16x4* obr = (bf16x4*)(ob + (size_t)row * 512);
    obr[lane] = c0;
    obr[lane + 64] = c1;
  }
}

// ---------------------------------------------------------------------------
// Tiled transpose + fp32->bf16 cast: per batch z, src [R][C] -> dst [C][R].
// ---------------------------------------------------------------------------
__global__ void transpose_cast(const float* __restrict__ src, bf16* __restrict__ dst,
                               int R, int C, int bpl, size_t lstride, size_t boff)
{
  __shared__ float t[32][33];
  const int z = blockIdx.z;
  src += (size_t)z * R * C;
  dst += (size_t)(z / bpl) * lstride + (size_t)(z % bpl) * ((size_t)R * C) + boff;
  const int c0 = blockIdx.x * 32, r0 = blockIdx.y * 32;
  const int tx = threadIdx.x, ty = threadIdx.y;   // (32, 8)
#pragma unroll
  for (int j = 0; j < 32; j += 8)
    t[ty + j][tx] = src[(size_t)(r0 + ty + j) * C + c0 + tx];
  __syncthreads();
#pragma unroll
  for (int j = 0; j < 32; j += 8)
    dst[(size_t)(c0 + ty + j) * R + r0 + tx] = (bf16)t[tx][ty + j];
}

__global__ void cast4(const float* __restrict__ s, bf16* __restrict__ d)
{
  const int i = blockIdx.x * 256 + threadIdx.x;
  const f32x4 v = ((const f32x4*)s)[i];
  bf16x4 c;
#pragma unroll
  for (int e = 0; e < 4; ++e) c[e] = (bf16)v[e];
  ((bf16x4*)d)[i] = c;
}

// ---------------------------------------------------------------------------
extern "C" void kernel_launch(void* const* d_in, const int* in_sizes, int n_in,
                              void* d_out, int out_size, void* d_ws, size_t ws_size,
                              hipStream_t stream)
{
  (void)in_sizes; (void)n_in; (void)out_size; (void)ws_size;
  const float* x   = (const float*)d_in[0];
  const float* y   = (const float*)d_in[1];
  const float* Wq1 = (const float*)d_in[2];
  const float* Wk1 = (const float*)d_in[3];
  const float* Wv1 = (const float*)d_in[4];
  const float* Wo1 = (const float*)d_in[5];
  const float* Wq2 = (const float*)d_in[6];
  const float* Wk2 = (const float*)d_in[7];
  const float* Wv2 = (const float*)d_in[8];
  const float* Wo2 = (const float*)d_in[9];
  const float* W1  = (const float*)d_in[10];
  const float* b1  = (const float*)d_in[11];
  const float* W2  = (const float*)d_in[12];
  const float* b2  = (const float*)d_in[13];
  const float* ln1g = (const float*)d_in[14];
  const float* ln1b = (const float*)d_in[15];
  const float* ln2g = (const float*)d_in[16];
  const float* ln2b = (const float*)d_in[17];
  const float* ln3g = (const float*)d_in[18];
  const float* ln3b = (const float*)d_in[19];

  char* ws = (char*)d_ws;
  size_t off = 0;
  auto alloc = [&](size_t bytes) -> void* {
    void* p = (void*)(ws + off);
    off += (bytes + 255) & ~(size_t)255;
    return p;
  };

  // weights (bf16, [N][K] transposed)
  bf16* wqkv1t = (bf16*)alloc((size_t)6 * 1536 * 512 * 2);
  bf16* wo1t   = (bf16*)alloc((size_t)6 * 512 * 512 * 2);
  bf16* wq2t   = (bf16*)alloc((size_t)6 * 512 * 512 * 2);
  bf16* wkv2t  = (bf16*)alloc((size_t)6 * 1024 * 512 * 2);
  bf16* wo2t   = (bf16*)alloc((size_t)6 * 512 * 512 * 2);
  bf16* w1t    = (bf16*)alloc((size_t)6 * 512 * 2048 * 2);
  bf16* w2t    = (bf16*)alloc((size_t)6 * 2048 * 512 * 2);
  // activations
  bf16* xb   = (bf16*)alloc((size_t)8192 * 512 * 2);
  bf16* yb   = (bf16*)alloc((size_t)8192 * 512 * 2);
  bf16* qkvb = (bf16*)alloc((size_t)8192 * 1536 * 2);
  bf16* qb   = (bf16*)alloc((size_t)8192 * 512 * 2);   // contiguous after qkvb
  bf16* kvb  = (bf16*)alloc((size_t)8192 * 1024 * 2);
  bf16* ab   = (bf16*)alloc((size_t)8192 * 512 * 2);
  bf16* h1b  = (bf16*)alloc((size_t)8192 * 512 * 2);
  bf16* h2b  = (bf16*)alloc((size_t)8192 * 512 * 2);
  float* zf  = (float*)alloc((size_t)8192 * 512 * 4);
  bf16* vt1  = (bf16*)alloc((size_t)8192 * 512 * 2);   // V^T self-attn
  bf16* f1b  = qkvb;          // aliases qkvb+qb (33.5 MB), both dead during FFN
  bf16* vt2  = qkvb;          // V^T cross-attn; qkvb dead after self-attn

  // --- weight prep ---
  const dim3 tb(32, 8);
  transpose_cast<<<dim3(2, 16, 48), tb, 0, stream>>>(Wq1, wqkv1t, 512, 64, 8, (size_t)1536 * 512, 0);
  transpose_cast<<<dim3(2, 16, 48), tb, 0, stream>>>(Wk1, wqkv1t, 512, 64, 8, (size_t)1536 * 512, (size_t)512 * 512);
  transpose_cast<<<dim3(2, 16, 48), tb, 0, stream>>>(Wv1, wqkv1t, 512, 64, 8, (size_t)1536 * 512, (size_t)1024 * 512);
  transpose_cast<<<dim3(16, 16, 6), tb, 0, stream>>>(Wo1, wo1t, 512, 512, 1, (size_t)512 * 512, 0);
  transpose_cast<<<dim3(2, 16, 48), tb, 0, stream>>>(Wq2, wq2t, 512, 64, 8, (size_t)512 * 512, 0);
  transpose_cast<<<dim3(2, 16, 48), tb, 0, stream>>>(Wk2, wkv2t, 512, 64, 8, (size_t)1024 * 512, 0);
  transpose_cast<<<dim3(2, 16, 48), tb, 0, stream>>>(Wv2, wkv2t, 512, 64, 8, (size_t)1024 * 512, (size_t)512 * 512);
  transpose_cast<<<dim3(16, 16, 6), tb, 0, stream>>>(Wo2, wo2t, 512, 512, 1, (size_t)512 * 512, 0);
  transpose_cast<<<dim3(64, 16, 6), tb, 0, stream>>>(W1, w1t, 512, 2048, 1, (size_t)512 * 2048, 0);
  transpose_cast<<<dim3(16, 64, 6), tb, 0, stream>>>(W2, w2t, 2048, 512, 1, (size_t)2048 * 512, 0);
  cast4<<<4096, 256, 0, stream>>>(x, xb);
  cast4<<<4096, 256, 0, stream>>>(y, yb);

  const bf16* curxb = xb;
  const dim3 g512s(8, 64), g1024s(16, 64), g1536(12, 64), gff(16, 64);
  const dim3 vtg(8, 1, 128), vtb(64, 4);

  for (int l = 0; l < 6; ++l) {
    const bf16* WQKV1 = wqkv1t + (size_t)l * 1536 * 512;
    const bf16* WO1   = wo1t   + (size_t)l * 512 * 512;
    const bf16* WQ2   = wq2t   + (size_t)l * 512 * 512;
    const bf16* WKV2  = wkv2t  + (size_t)l * 1024 * 512;
    const bf16* WO2   = wo2t   + (size_t)l * 512 * 512;
    const bf16* W1T   = w1t    + (size_t)l * 2048 * 512;
    const bf16* W2T   = w2t    + (size_t)l * 512 * 2048;

    // masked self-attention + residual + LN1
    gemm_k<128, 0, 0, 0, 1><<<g1536, 256, 0, stream>>>(curxb, WQKV1, nullptr, qkvb,
                                                       nullptr, nullptr, 8192, 1536, 512);
    vtrans<<<vtg, vtb, 0, stream>>>(qkvb + 1024, vt1, 1536);
    attn_k<1><<<dim3(8, 8, 16), 256, 0, stream>>>(qkvb, qkvb + 512, vt1, ab, 1536, 1536);
    gemm_k<64, 0, 0, 1, 0><<<g512s, 256, 0, stream>>>(ab, WO1, zf, nullptr,
                                                      nullptr, curxb, 8192, 512, 512);
    ln_k<<<2048, 256, 0, stream>>>(zf, ln1g + l * 512, ln1b + l * 512, nullptr, h1b);

    // cross-attention + residual + LN2
    gemm_k<64, 0, 0, 0, 1><<<g512s, 256, 0, stream>>>(h1b, WQ2, nullptr, qb,
                                                      nullptr, nullptr, 8192, 512, 512);
    gemm_k<64, 0, 0, 0, 1><<<g1024s, 256, 0, stream>>>(yb, WKV2, nullptr, kvb,
                                                       nullptr, nullptr, 8192, 1024, 512);
    vtrans<<<vtg, vtb, 0, stream>>>(kvb + 512, vt2, 1024);
    attn_k<0><<<dim3(8, 8, 16), 256, 0, stream>>>(qb, kvb, vt2, ab, 512, 1024);
    gemm_k<64, 0, 0, 1, 0><<<g512s, 256, 0, stream>>>(ab, WO2, zf, nullptr,
                                                      nullptr, h1b, 8192, 512, 512);
    ln_k<<<2048, 256, 0, stream>>>(zf, ln2g + l * 512, ln2b + l * 512, nullptr, h2b);

    // FFN + residual + LN3
    gemm_k<128, 1, 1, 0, 1><<<gff, 256, 0, stream>>>(h2b, W1T, nullptr, f1b,
                                                     b1 + l * 2048, nullptr, 8192, 2048, 512);
    gemm_k<64, 0, 1, 1, 0><<<g512s, 256, 0, stream>>>(f1b, W2T, zf, nullptr,
                                                      b2 + l * 512, h2b, 8192, 512, 2048);
    float* outf = (l == 5) ? (float*)d_out : nullptr;
    bf16* outb  = (l == 5) ? nullptr : xb;
    ln_k<<<2048, 256, 0, stream>>>(zf, ln3g + l * 512, ln3b + l * 512, outf, outb);
    curxb = xb;
  }
}

// Round 9
// 1288.018 us; speedup vs baseline: 1.1003x; 1.1003x over previous
//
#include <hip/hip_runtime.h>

typedef __bf16 bf16;
typedef __attribute__((ext_vector_type(8))) __bf16 bf16x8;
typedef __attribute__((ext_vector_type(4))) __bf16 bf16x4;
typedef __attribute__((ext_vector_type(4))) float f32x4;

#define GL16(gp, lp) __builtin_amdgcn_global_load_lds( \
    (const __attribute__((address_space(1))) unsigned int*)(gp), \
    (__attribute__((address_space(3))) unsigned int*)(lp), 16, 0, 0)

__device__ __forceinline__ f32x4 mfma16(bf16x8 a, bf16x8 b, f32x4 c) {
  return __builtin_amdgcn_mfma_f32_16x16x32_bf16(a, b, c, 0, 0, 0);
}

// ---------------------------------------------------------------------------
// Generic bf16 GEMM: C[M][N] = A[M][K] (bf16, row-major) * Bt[N][K]^T (bf16)
// BM=128 x BN tile, BK=64 (16-32 MFMA per wave per barrier interval -- the
// per-step fixed cost of barrier+drain is amortized over 2x the work vs BK=32).
// 2 LDS buffers, m97-proven order: vmcnt(0); s_barrier; stage(next); compute.
// Byte-XOR swizzle (c ^= (row&7)<<4) on both sides -> <=2-way LDS banks.
// BN=64: 48KB LDS, 3 blocks/CU. BN=128: 64KB, 2 blocks/CU. XCD block swizzle.
// Optional: bias (fp32), residual (bf16), ReLU, bf16/fp32 out, and VTO:
// blocks with bn >= vtc0 write their output TRANSPOSED into vt
// [b*8+h][dh 64][t 512] instead of C (fuses the V^T precompute).
// ---------------------------------------------------------------------------
template<int BN, int RELU, int BIAS, int RES, int OUTB, int VTO>
__global__ __launch_bounds__(256, (BN == 64) ? 3 : 2) void gemm_k(
    const bf16* __restrict__ A, const bf16* __restrict__ Bt,
    float* __restrict__ Cf, bf16* __restrict__ Cb,
    const float* __restrict__ bias, const bf16* __restrict__ resid,
    bf16* __restrict__ vt, int vtc0,
    int M, int N, int K)
{
  constexpr int MI = 4;             // wave tile 64 rows
  constexpr int NI = BN / 32;       // wave tile 64 (BN=128) or 32 (BN=64) cols
  __shared__ __align__(16) bf16 Al[2][128 * 64];
  __shared__ __align__(16) bf16 Bl[2][BN * 64];
  const int tid = threadIdx.x;
  const int wid = tid >> 6, lane = tid & 63;
  const int g = lane >> 4, l16 = lane & 15;

  // XCD swizzle: HW assigns XCD = lin%8; give each XCD a contiguous tile range
  int lin = blockIdx.x + gridDim.x * blockIdx.y;
  const int nwg = gridDim.x * gridDim.y;
  if ((nwg & 7) == 0) lin = (lin & 7) * (nwg >> 3) + (lin >> 3);
  const int bx = lin % gridDim.x, by = lin / gridDim.x;

  const int bm = by * 128, bn = bx * BN;
  const int wm = (wid >> 1) * 64;
  const int wn = (wid & 1) * (BN / 2);

  const f32x4 z4 = {0.f, 0.f, 0.f, 0.f};
  f32x4 acc[MI][NI];
#pragma unroll
  for (int i = 0; i < MI; ++i)
#pragma unroll
    for (int j = 0; j < NI; ++j) acc[i][j] = z4;

  // staging: sweep covers 32 rows x 64 cols (4KB). sr = tid>>3 (0..31),
  // slot byte = (tid&7)*16; source col byte pre-swizzled with ^((sr&7)<<4)
  // so LDS[row][c] = G[row][c ^ ((row&7)<<4)].
  const int sr = tid >> 3;
  const int scs = ((((tid & 7) * 16) ^ ((sr & 7) << 4)) >> 1);  // elems
  const bf16* Ag = A + (size_t)(bm + sr) * K + scs;
  const bf16* Bg = Bt + (size_t)(bn + sr) * K + scs;
  const size_t kstep32 = (size_t)32 * K;

  auto stage = [&](int sel, int k0) {
#pragma unroll
    for (int sw = 0; sw < 4; ++sw)
      GL16(Ag + k0 + sw * kstep32, &Al[sel][sw * 2048 + tid * 8]);
#pragma unroll
    for (int sw = 0; sw < BN / 32; ++sw)
      GL16(Bg + k0 + sw * kstep32, &Bl[sel][sw * 2048 + tid * 8]);
  };

  const int nsteps = K >> 6;
  stage(0, 0);
  int cur = 0;
  for (int s = 0; s < nsteps; ++s) {
    __builtin_amdgcn_sched_barrier(0);
    asm volatile("s_waitcnt vmcnt(0)" ::: "memory");
    __builtin_amdgcn_s_barrier();
    __builtin_amdgcn_sched_barrier(0);
    if (s + 1 < nsteps) stage(cur ^ 1, (s + 1) * 64);  // prefetch next K-step
    bf16x8 af[MI][2], bfr[NI][2];
#pragma unroll
    for (int mi = 0; mi < MI; ++mi) {
      const int row = wm + mi * 16 + l16;
      const int rs = (row & 7) << 4;
#pragma unroll
      for (int kh = 0; kh < 2; ++kh)
        af[mi][kh] = *(const bf16x8*)&Al[cur][row * 64 + (((g * 16 + kh * 64) ^ rs) >> 1)];
    }
#pragma unroll
    for (int ni = 0; ni < NI; ++ni) {
      const int row = wn + ni * 16 + l16;
      const int rs = (row & 7) << 4;
#pragma unroll
      for (int kh = 0; kh < 2; ++kh)
        bfr[ni][kh] = *(const bf16x8*)&Bl[cur][row * 64 + (((g * 16 + kh * 64) ^ rs) >> 1)];
    }
#pragma unroll
    for (int kh = 0; kh < 2; ++kh)
#pragma unroll
      for (int mi = 0; mi < MI; ++mi)
#pragma unroll
        for (int ni = 0; ni < NI; ++ni)
          acc[mi][ni] = mfma16(af[mi][kh], bfr[ni][kh], acc[mi][ni]);
    cur ^= 1;
  }

  if (VTO && bn >= vtc0) {
    // write transposed: VT[(b*8+h)][dh][t], 4 consecutive t per thread (8B)
#pragma unroll
    for (int mi = 0; mi < MI; ++mi) {
#pragma unroll
      for (int ni = 0; ni < NI; ++ni) {
        const int row0 = bm + wm + mi * 16 + g * 4;   // token; 4 consecutive
        const int gdh = bn + wn + ni * 16 + l16 - vtc0;
        const int bh = (row0 >> 9) * 8 + (gdh >> 6);
        const int t0 = row0 & 511;
        bf16x4 v4;
#pragma unroll
        for (int r = 0; r < 4; ++r) v4[r] = (bf16)acc[mi][ni][r];
        *(bf16x4*)&vt[((size_t)bh * 64 + (gdh & 63)) * 512 + t0] = v4;
      }
    }
    return;
  }

#pragma unroll
  for (int mi = 0; mi < MI; ++mi) {
#pragma unroll
    for (int ni = 0; ni < NI; ++ni) {
#pragma unroll
      for (int r = 0; r < 4; ++r) {
        const int row = bm + wm + mi * 16 + g * 4 + r;
        const int col = bn + wn + ni * 16 + l16;
        float v = acc[mi][ni][r];
        if (BIAS) v += bias[col];
        const size_t idx = (size_t)row * N + col;
        if (RES)  v += (float)resid[idx];
        if (RELU) v = fmaxf(v, 0.f);
        if (OUTB) Cb[idx] = (bf16)v;
        else      Cf[idx] = v;
      }
    }
  }
}

// ---------------------------------------------------------------------------
// Flash attention, MFMA. One block = (b, h, 64-row q tile), 4 waves x 16 q
// rows. KV tiles of 64, double-buffered + 1-deep prefetch. K/V^T staged via
// global_load_lds (linear dest) with XOR-swizzled global source column;
// ds_read_b128 fragment reads conflict-free. V^T produced by the QKV/KV
// GEMMs: VT [b*8+h][64 dh][512 t]. P per-wave in LDS, same swizzle.
// XCD swizzle: 8 q-tile blocks of one (b,h) colocate -> K/V L2 reuse.
// ---------------------------------------------------------------------------
template<int CAUSAL>
__global__ __launch_bounds__(256, 4) void attn_k(
    const bf16* __restrict__ Q, const bf16* __restrict__ Kg,
    const bf16* __restrict__ VT, bf16* __restrict__ O, int qs, int kvs)
{
  __shared__ __align__(16) bf16 Kl[2][64 * 64];
  __shared__ __align__(16) bf16 Vl[2][64 * 64];
  __shared__ __align__(16) bf16 plb[4 * 16 * 64];
  const int tid = threadIdx.x;
  const int wid = tid >> 6, lane = tid & 63;
  const int g = lane >> 4, l16 = lane & 15;

  // grid (8,8,16) flattened; XCD swizzle (nwg=1024, q=128)
  int lin = blockIdx.x + 8 * blockIdx.y + 64 * blockIdx.z;
  lin = (lin & 7) * 128 + (lin >> 3);
  const int qt = lin & 7, h = (lin >> 3) & 7, b = lin >> 6;

  const int q0 = qt * 64 + wid * 16;
  const size_t tokQ = (size_t)b * 512 + q0;

  const bf16* qp = Q + (tokQ + l16) * (size_t)qs + h * 64 + g * 8;
  const bf16x8 qf0 = *(const bf16x8*)qp;
  const bf16x8 qf1 = *(const bf16x8*)(qp + 32);

  // staging source: row sr = tid>>3, swizzled col (both-sides pattern)
  const int sr = tid >> 3;
  const int cs2 = ((((tid & 7) * 16) ^ ((sr & 7) << 4)) >> 1);  // bf16 elems
  const bf16* Ksrc = Kg + ((size_t)b * 512 + sr) * kvs + h * 64 + cs2;
  const bf16* Vsrc = VT + (size_t)(b * 8 + h) * 64 * 512 + (size_t)sr * 512 + cs2;
  bf16* pw = plb + wid * 1024;

  auto stage = [&](int sel, int t0) {
    GL16(Ksrc + (size_t)t0 * kvs, &Kl[sel][tid * 8]);
    GL16(Ksrc + (size_t)(t0 + 32) * kvs, &Kl[sel][tid * 8 + 2048]);
    GL16(Vsrc + t0, &Vl[sel][tid * 8]);
    GL16(Vsrc + 32 * 512 + t0, &Vl[sel][tid * 8 + 2048]);
  };

  const f32x4 z4 = {0.f, 0.f, 0.f, 0.f};
  float m[4], ls[4];
  f32x4 o[4];
#pragma unroll
  for (int r = 0; r < 4; ++r) { m[r] = -1e30f; ls[r] = 0.f; o[r] = z4; }

  const int sw = (l16 & 7) << 4;   // byte swizzle for fragment reads
  const int ktmax = CAUSAL ? qt : 7;
  stage(0, 0);
  int cur = 0;
  for (int kt = 0; kt <= ktmax; ++kt) {
    const int t0 = kt * 64;
    __builtin_amdgcn_sched_barrier(0);
    asm volatile("s_waitcnt vmcnt(0)" ::: "memory");
    __builtin_amdgcn_s_barrier();
    if (kt < ktmax) stage(cur ^ 1, t0 + 64);    // prefetch next KV tile

    // QK^T -> 4 16x16 tiles per wave (t cols t0 + jt*16 + l16)
    f32x4 sc[4];
#pragma unroll
    for (int jt = 0; jt < 4; ++jt) {
      const int rk = jt * 16 + l16;
      const bf16x8 kf0 = *(const bf16x8*)&Kl[cur][rk * 64 + (((g * 16) ^ sw) >> 1)];
      const bf16x8 kf1 = *(const bf16x8*)&Kl[cur][rk * 64 + (((g * 16 + 64) ^ sw) >> 1)];
      sc[jt] = mfma16(qf0, kf0, z4);
      sc[jt] = mfma16(qf1, kf1, sc[jt]);
    }
    // online softmax per row r (row q = g*4+r, col = jt*16+l16)
#pragma unroll
    for (int r = 0; r < 4; ++r) {
      const int q = g * 4 + r;
      const int srow = q0 + q;
      const int qs7 = (q & 7) << 4;
      float pv[4];
      float mx = -1e30f;
#pragma unroll
      for (int jt = 0; jt < 4; ++jt) {
        float v = sc[jt][r] * 0.125f;   // 1/sqrt(64)
        if (CAUSAL && (t0 + jt * 16 + l16) > srow) v = -1e30f;
        pv[jt] = v;
        mx = fmaxf(mx, v);
      }
#pragma unroll
      for (int msk = 8; msk; msk >>= 1) mx = fmaxf(mx, __shfl_xor(mx, msk));
      const float mn = fmaxf(m[r], mx);
      const float corr = __expf(m[r] - mn);
      float s = 0.f;
#pragma unroll
      for (int jt = 0; jt < 4; ++jt) {
        const float p = __expf(pv[jt] - mn);
        s += p;
        const int sb = (((jt * 16 + l16) * 2) ^ qs7) >> 1;
        pw[q * 64 + sb] = (bf16)p;
      }
#pragma unroll
      for (int msk = 8; msk; msk >>= 1) s += __shfl_xor(s, msk);
      ls[r] = ls[r] * corr + s;
      m[r] = mn;
#pragma unroll
      for (int j = 0; j < 4; ++j) o[j][r] *= corr;
    }
    // same-wave LDS visibility for P (no cross-wave sharing of P)
    asm volatile("s_waitcnt lgkmcnt(0)" ::: "memory");
    __builtin_amdgcn_sched_barrier(0);
    const bf16x8 pa0 = *(const bf16x8*)&pw[l16 * 64 + (((g * 16) ^ sw) >> 1)];
    const bf16x8 pa1 = *(const bf16x8*)&pw[l16 * 64 + (((g * 16 + 64) ^ sw) >> 1)];
#pragma unroll
    for (int j = 0; j < 4; ++j) {
      const int rv = j * 16 + l16;
      const bf16x8 vf0 = *(const bf16x8*)&Vl[cur][rv * 64 + (((g * 16) ^ sw) >> 1)];
      const bf16x8 vf1 = *(const bf16x8*)&Vl[cur][rv * 64 + (((g * 16 + 64) ^ sw) >> 1)];
      o[j] = mfma16(pa0, vf0, o[j]);
      o[j] = mfma16(pa1, vf1, o[j]);
    }
    cur ^= 1;
  }
#pragma unroll
  for (int r = 0; r < 4; ++r) {
    const float inv = 1.f / ls[r];
    bf16* op = O + (tokQ + g * 4 + r) * 512 + h * 64;
#pragma unroll
    for (int j = 0; j < 4; ++j) op[j * 16 + l16] = (bf16)(o[j][r] * inv);
  }
}

// ---------------------------------------------------------------------------
// LayerNorm over D=512. One wave per row; fp32 math; writes bf16 and/or fp32.
// ---------------------------------------------------------------------------
__global__ __launch_bounds__(256) void ln_k(
    const float* __restrict__ z, const float* __restrict__ gam,
    const float* __restrict__ bet, float* __restrict__ of,
    bf16* __restrict__ ob)
{
  const int wid = threadIdx.x >> 6, lane = threadIdx.x & 63;
  const int row = blockIdx.x * 4 + wid;
  const f32x4* zr = (const f32x4*)(z + (size_t)row * 512);
  const f32x4 a = zr[lane], c = zr[lane + 64];
  float s = 0.f, ss = 0.f;
#pragma unroll
  for (int e = 0; e < 4; ++e) {
    s += a[e] + c[e];
    ss += a[e] * a[e] + c[e] * c[e];
  }
#pragma unroll
  for (int msk = 32; msk; msk >>= 1) {
    s += __shfl_xor(s, msk);
    ss += __shfl_xor(ss, msk);
  }
  const float mean = s * (1.f / 512.f);
  const float var = ss * (1.f / 512.f) - mean * mean;
  const float rstd = rsqrtf(var + 1e-5f);
  const f32x4* gp = (const f32x4*)gam;
  const f32x4* bp = (const f32x4*)bet;
  const f32x4 g0 = gp[lane], g1 = gp[lane + 64];
  const f32x4 b0 = bp[lane], b1 = bp[lane + 64];
  f32x4 o0, o1;
#pragma unroll
  for (int e = 0; e < 4; ++e) {
    o0[e] = (a[e] - mean) * rstd * g0[e] + b0[e];
    o1[e] = (c[e] - mean) * rstd * g1[e] + b1[e];
  }
  if (of) {
    f32x4* ofr = (f32x4*)(of + (size_t)row * 512);
    ofr[lane] = o0;
    ofr[lane + 64] = o1;
  }
  if (ob) {
    bf16x4 c0, c1;
#pragma unroll
    for (int e = 0; e < 4; ++e) { c0[e] = (bf16)o0[e]; c1[e] = (bf16)o1[e]; }
    bf16x4* obr = (bf16x4*)(ob + (size_t)row * 512);
    obr[lane] = c0;
    obr[lane + 64] = c1;
  }
}

// ---------------------------------------------------------------------------
// Tiled transpose + fp32->bf16 cast: per batch z, src [R][C] -> dst [C][R].
// ---------------------------------------------------------------------------
__global__ void transpose_cast(const float* __restrict__ src, bf16* __restrict__ dst,
                               int R, int C, int bpl, size_t lstride, size_t boff)
{
  __shared__ float t[32][33];
  const int z = blockIdx.z;
  src += (size_t)z * R * C;
  dst += (size_t)(z / bpl) * lstride + (size_t)(z % bpl) * ((size_t)R * C) + boff;
  const int c0 = blockIdx.x * 32, r0 = blockIdx.y * 32;
  const int tx = threadIdx.x, ty = threadIdx.y;   // (32, 8)
#pragma unroll
  for (int j = 0; j < 32; j += 8)
    t[ty + j][tx] = src[(size_t)(r0 + ty + j) * C + c0 + tx];
  __syncthreads();
#pragma unroll
  for (int j = 0; j < 32; j += 8)
    dst[(size_t)(c0 + ty + j) * R + r0 + tx] = (bf16)t[tx][ty + j];
}

__global__ void cast4(const float* __restrict__ s, bf16* __restrict__ d)
{
  const int i = blockIdx.x * 256 + threadIdx.x;
  const f32x4 v = ((const f32x4*)s)[i];
  bf16x4 c;
#pragma unroll
  for (int e = 0; e < 4; ++e) c[e] = (bf16)v[e];
  ((bf16x4*)d)[i] = c;
}

// ---------------------------------------------------------------------------
extern "C" void kernel_launch(void* const* d_in, const int* in_sizes, int n_in,
                              void* d_out, int out_size, void* d_ws, size_t ws_size,
                              hipStream_t stream)
{
  (void)in_sizes; (void)n_in; (void)out_size; (void)ws_size;
  const float* x   = (const float*)d_in[0];
  const float* y   = (const float*)d_in[1];
  const float* Wq1 = (const float*)d_in[2];
  const float* Wk1 = (const float*)d_in[3];
  const float* Wv1 = (const float*)d_in[4];
  const float* Wo1 = (const float*)d_in[5];
  const float* Wq2 = (const float*)d_in[6];
  const float* Wk2 = (const float*)d_in[7];
  const float* Wv2 = (const float*)d_in[8];
  const float* Wo2 = (const float*)d_in[9];
  const float* W1  = (const float*)d_in[10];
  const float* b1  = (const float*)d_in[11];
  const float* W2  = (const float*)d_in[12];
  const float* b2  = (const float*)d_in[13];
  const float* ln1g = (const float*)d_in[14];
  const float* ln1b = (const float*)d_in[15];
  const float* ln2g = (const float*)d_in[16];
  const float* ln2b = (const float*)d_in[17];
  const float* ln3g = (const float*)d_in[18];
  const float* ln3b = (const float*)d_in[19];

  char* ws = (char*)d_ws;
  size_t off = 0;
  auto alloc = [&](size_t bytes) -> void* {
    void* p = (void*)(ws + off);
    off += (bytes + 255) & ~(size_t)255;
    return p;
  };

  // weights (bf16, [N][K] transposed)
  bf16* wqkv1t = (bf16*)alloc((size_t)6 * 1536 * 512 * 2);
  bf16* wo1t   = (bf16*)alloc((size_t)6 * 512 * 512 * 2);
  bf16* wq2t   = (bf16*)alloc((size_t)6 * 512 * 512 * 2);
  bf16* wkv2t  = (bf16*)alloc((size_t)6 * 1024 * 512 * 2);
  bf16* wo2t   = (bf16*)alloc((size_t)6 * 512 * 512 * 2);
  bf16* w1t    = (bf16*)alloc((size_t)6 * 512 * 2048 * 2);
  bf16* w2t    = (bf16*)alloc((size_t)6 * 2048 * 512 * 2);
  // activations
  bf16* xb   = (bf16*)alloc((size_t)8192 * 512 * 2);
  bf16* yb   = (bf16*)alloc((size_t)8192 * 512 * 2);
  bf16* qkvb = (bf16*)alloc((size_t)8192 * 1536 * 2);
  bf16* qb   = (bf16*)alloc((size_t)8192 * 512 * 2);   // contiguous after qkvb
  bf16* kvb  = (bf16*)alloc((size_t)8192 * 1024 * 2);
  bf16* ab   = (bf16*)alloc((size_t)8192 * 512 * 2);
  bf16* h1b  = (bf16*)alloc((size_t)8192 * 512 * 2);
  bf16* h2b  = (bf16*)alloc((size_t)8192 * 512 * 2);
  float* zf  = (float*)alloc((size_t)8192 * 512 * 4);
  bf16* vt1  = (bf16*)alloc((size_t)8192 * 512 * 2);   // V^T self-attn
  bf16* f1b  = qkvb;          // aliases qkvb+qb (33.5 MB), both dead during FFN
  bf16* vt2  = qkvb;          // V^T cross-attn; qkvb dead after self-attn

  // --- weight prep ---
  const dim3 tb(32, 8);
  transpose_cast<<<dim3(2, 16, 48), tb, 0, stream>>>(Wq1, wqkv1t, 512, 64, 8, (size_t)1536 * 512, 0);
  transpose_cast<<<dim3(2, 16, 48), tb, 0, stream>>>(Wk1, wqkv1t, 512, 64, 8, (size_t)1536 * 512, (size_t)512 * 512);
  transpose_cast<<<dim3(2, 16, 48), tb, 0, stream>>>(Wv1, wqkv1t, 512, 64, 8, (size_t)1536 * 512, (size_t)1024 * 512);
  transpose_cast<<<dim3(16, 16, 6), tb, 0, stream>>>(Wo1, wo1t, 512, 512, 1, (size_t)512 * 512, 0);
  transpose_cast<<<dim3(2, 16, 48), tb, 0, stream>>>(Wq2, wq2t, 512, 64, 8, (size_t)512 * 512, 0);
  transpose_cast<<<dim3(2, 16, 48), tb, 0, stream>>>(Wk2, wkv2t, 512, 64, 8, (size_t)1024 * 512, 0);
  transpose_cast<<<dim3(2, 16, 48), tb, 0, stream>>>(Wv2, wkv2t, 512, 64, 8, (size_t)1024 * 512, (size_t)512 * 512);
  transpose_cast<<<dim3(16, 16, 6), tb, 0, stream>>>(Wo2, wo2t, 512, 512, 1, (size_t)512 * 512, 0);
  transpose_cast<<<dim3(64, 16, 6), tb, 0, stream>>>(W1, w1t, 512, 2048, 1, (size_t)512 * 2048, 0);
  transpose_cast<<<dim3(16, 64, 6), tb, 0, stream>>>(W2, w2t, 2048, 512, 1, (size_t)2048 * 512, 0);
  cast4<<<4096, 256, 0, stream>>>(x, xb);
  cast4<<<4096, 256, 0, stream>>>(y, yb);

  const bf16* curxb = xb;
  const dim3 g512s(8, 64), g1024s(16, 64), g1536(12, 64), gff(16, 64);

  for (int l = 0; l < 6; ++l) {
    const bf16* WQKV1 = wqkv1t + (size_t)l * 1536 * 512;
    const bf16* WO1   = wo1t   + (size_t)l * 512 * 512;
    const bf16* WQ2   = wq2t   + (size_t)l * 512 * 512;
    const bf16* WKV2  = wkv2t  + (size_t)l * 1024 * 512;
    const bf16* WO2   = wo2t   + (size_t)l * 512 * 512;
    const bf16* W1T   = w1t    + (size_t)l * 2048 * 512;
    const bf16* W2T   = w2t    + (size_t)l * 512 * 2048;

    // masked self-attention + residual + LN1 (QKV gemm writes V^T directly)
    gemm_k<128, 0, 0, 0, 1, 1><<<g1536, 256, 0, stream>>>(curxb, WQKV1, nullptr, qkvb,
                                                          nullptr, nullptr, vt1, 1024, 8192, 1536, 512);
    attn_k<1><<<dim3(8, 8, 16), 256, 0, stream>>>(qkvb, qkvb + 512, vt1, ab, 1536, 1536);
    gemm_k<64, 0, 0, 1, 0, 0><<<g512s, 256, 0, stream>>>(ab, WO1, zf, nullptr,
                                                         nullptr, curxb, nullptr, 0, 8192, 512, 512);
    ln_k<<<2048, 256, 0, stream>>>(zf, ln1g + l * 512, ln1b + l * 512, nullptr, h1b);

    // cross-attention + residual + LN2 (KV gemm writes V^T directly)
    gemm_k<64, 0, 0, 0, 1, 0><<<g512s, 256, 0, stream>>>(h1b, WQ2, nullptr, qb,
                                                         nullptr, nullptr, nullptr, 0, 8192, 512, 512);
    gemm_k<64, 0, 0, 0, 1, 1><<<g1024s, 256, 0, stream>>>(yb, WKV2, nullptr, kvb,
                                                          nullptr, nullptr, vt2, 512, 8192, 1024, 512);
    attn_k<0><<<dim3(8, 8, 16), 256, 0, stream>>>(qb, kvb, vt2, ab, 512, 1024);
    gemm_k<64, 0, 0, 1, 0, 0><<<g512s, 256, 0, stream>>>(ab, WO2, zf, nullptr,
                                                         nullptr, h1b, nullptr, 0, 8192, 512, 512);
    ln_k<<<2048, 256, 0, stream>>>(zf, ln2g + l * 512, ln2b + l * 512, nullptr, h2b);

    // FFN + residual + LN3
    gemm_k<128, 1, 1, 0, 1, 0><<<gff, 256, 0, stream>>>(h2b, W1T, nullptr, f1b,
                                                        b1 + l * 2048, nullptr, nullptr, 0, 8192, 2048, 512);
    gemm_k<64, 0, 1, 1, 0, 0><<<g512s, 256, 0, stream>>>(f1b, W2T, zf, nullptr,
                                                         b2 + l * 512, h2b, nullptr, 0, 8192, 512, 2048);
    float* outf = (l == 5) ? (float*)d_out : nullptr;
    bf16* outb  = (l == 5) ? nullptr : xb;
    ln_k<<<2048, 256, 0, stream>>>(zf, ln3g + l * 512, ln3b + l * 512, outf, outb);
    curxb = xb;
  }
}

// Round 10
// 1269.223 us; speedup vs baseline: 1.1166x; 1.0148x over previous
//
#include <hip/hip_runtime.h>

typedef __bf16 bf16;
typedef __attribute__((ext_vector_type(8))) __bf16 bf16x8;
typedef __attribute__((ext_vector_type(4))) __bf16 bf16x4;
typedef __attribute__((ext_vector_type(4))) float f32x4;

#define GL16(gp, lp) __builtin_amdgcn_global_load_lds( \
    (const __attribute__((address_space(1))) unsigned int*)(gp), \
    (__attribute__((address_space(3))) unsigned int*)(lp), 16, 0, 0)

__device__ __forceinline__ f32x4 mfma16(bf16x8 a, bf16x8 b, f32x4 c) {
  return __builtin_amdgcn_mfma_f32_16x16x32_bf16(a, b, c, 0, 0, 0);
}

// ---------------------------------------------------------------------------
// Generic bf16 GEMM: C[M][N] = A[M][K] (bf16, row-major) * Bt[N][K]^T (bf16)
// BM=128 x BN tile, BK=64 (32/16 MFMA per wave per barrier interval).
// 2 LDS buffers, m97-proven order: vmcnt(0); s_barrier; stage(next); compute.
// Byte-XOR swizzle (c ^= (row&7)<<4) on both sides -> <=2-way LDS banks.
// BN=64: 48KB LDS, 3 blocks/CU. BN=128: 64KB, 2 blocks/CU. XCD block swizzle.
// Optional: bias (fp32), residual (bf16), ReLU, bf16/fp32 out, and VTO:
// blocks with bn >= vtc0 write output TRANSPOSED into vt with layout
// [l][b*8+h][dh 64][t 512], where gdh = col-vtc0, l = gdh>>9, h = (gdh>>6)&7
// (fuses the V^T precompute; supports multi-layer stacked N).
// ---------------------------------------------------------------------------
template<int BN, int RELU, int BIAS, int RES, int OUTB, int VTO>
__global__ __launch_bounds__(256, (BN == 64) ? 3 : 2) void gemm_k(
    const bf16* __restrict__ A, const bf16* __restrict__ Bt,
    float* __restrict__ Cf, bf16* __restrict__ Cb,
    const float* __restrict__ bias, const bf16* __restrict__ resid,
    bf16* __restrict__ vt, int vtc0,
    int M, int N, int K)
{
  constexpr int MI = 4;             // wave tile 64 rows
  constexpr int NI = BN / 32;       // wave tile 64 (BN=128) or 32 (BN=64) cols
  __shared__ __align__(16) bf16 Al[2][128 * 64];
  __shared__ __align__(16) bf16 Bl[2][BN * 64];
  const int tid = threadIdx.x;
  const int wid = tid >> 6, lane = tid & 63;
  const int g = lane >> 4, l16 = lane & 15;

  // XCD swizzle: HW assigns XCD = lin%8; give each XCD a contiguous tile range
  int lin = blockIdx.x + gridDim.x * blockIdx.y;
  const int nwg = gridDim.x * gridDim.y;
  if ((nwg & 7) == 0) lin = (lin & 7) * (nwg >> 3) + (lin >> 3);
  const int bx = lin % gridDim.x, by = lin / gridDim.x;

  const int bm = by * 128, bn = bx * BN;
  const int wm = (wid >> 1) * 64;
  const int wn = (wid & 1) * (BN / 2);

  const f32x4 z4 = {0.f, 0.f, 0.f, 0.f};
  f32x4 acc[MI][NI];
#pragma unroll
  for (int i = 0; i < MI; ++i)
#pragma unroll
    for (int j = 0; j < NI; ++j) acc[i][j] = z4;

  // staging: sweep covers 32 rows x 64 cols (4KB). sr = tid>>3 (0..31),
  // slot byte = (tid&7)*16; source col byte pre-swizzled with ^((sr&7)<<4)
  // so LDS[row][c] = G[row][c ^ ((row&7)<<4)].
  const int sr = tid >> 3;
  const int scs = ((((tid & 7) * 16) ^ ((sr & 7) << 4)) >> 1);  // elems
  const bf16* Ag = A + (size_t)(bm + sr) * K + scs;
  const bf16* Bg = Bt + (size_t)(bn + sr) * K + scs;
  const size_t kstep32 = (size_t)32 * K;

  auto stage = [&](int sel, int k0) {
#pragma unroll
    for (int sw = 0; sw < 4; ++sw)
      GL16(Ag + k0 + sw * kstep32, &Al[sel][sw * 2048 + tid * 8]);
#pragma unroll
    for (int sw = 0; sw < BN / 32; ++sw)
      GL16(Bg + k0 + sw * kstep32, &Bl[sel][sw * 2048 + tid * 8]);
  };

  const int nsteps = K >> 6;
  stage(0, 0);
  int cur = 0;
  for (int s = 0; s < nsteps; ++s) {
    __builtin_amdgcn_sched_barrier(0);
    asm volatile("s_waitcnt vmcnt(0)" ::: "memory");
    __builtin_amdgcn_s_barrier();
    __builtin_amdgcn_sched_barrier(0);
    if (s + 1 < nsteps) stage(cur ^ 1, (s + 1) * 64);  // prefetch next K-step
    bf16x8 af[MI][2], bfr[NI][2];
#pragma unroll
    for (int mi = 0; mi < MI; ++mi) {
      const int row = wm + mi * 16 + l16;
      const int rs = (row & 7) << 4;
#pragma unroll
      for (int kh = 0; kh < 2; ++kh)
        af[mi][kh] = *(const bf16x8*)&Al[cur][row * 64 + (((g * 16 + kh * 64) ^ rs) >> 1)];
    }
#pragma unroll
    for (int ni = 0; ni < NI; ++ni) {
      const int row = wn + ni * 16 + l16;
      const int rs = (row & 7) << 4;
#pragma unroll
      for (int kh = 0; kh < 2; ++kh)
        bfr[ni][kh] = *(const bf16x8*)&Bl[cur][row * 64 + (((g * 16 + kh * 64) ^ rs) >> 1)];
    }
#pragma unroll
    for (int kh = 0; kh < 2; ++kh)
#pragma unroll
      for (int mi = 0; mi < MI; ++mi)
#pragma unroll
        for (int ni = 0; ni < NI; ++ni)
          acc[mi][ni] = mfma16(af[mi][kh], bfr[ni][kh], acc[mi][ni]);
    cur ^= 1;
  }

  if (VTO && bn >= vtc0) {
    // write transposed: vt[l][b*8+h][dh][t], 4 consecutive t per thread (8B)
#pragma unroll
    for (int mi = 0; mi < MI; ++mi) {
#pragma unroll
      for (int ni = 0; ni < NI; ++ni) {
        const int row0 = bm + wm + mi * 16 + g * 4;   // token; 4 consecutive
        const int gdh = bn + wn + ni * 16 + l16 - vtc0;
        const int l = gdh >> 9, h = (gdh >> 6) & 7, dh = gdh & 63;
        const int b = row0 >> 9, t0 = row0 & 511;
        bf16x4 v4;
#pragma unroll
        for (int r = 0; r < 4; ++r) v4[r] = (bf16)acc[mi][ni][r];
        *(bf16x4*)&vt[(((size_t)l * 128 + b * 8 + h) * 64 + dh) * 512 + t0] = v4;
      }
    }
    return;
  }

#pragma unroll
  for (int mi = 0; mi < MI; ++mi) {
#pragma unroll
    for (int ni = 0; ni < NI; ++ni) {
#pragma unroll
      for (int r = 0; r < 4; ++r) {
        const int row = bm + wm + mi * 16 + g * 4 + r;
        const int col = bn + wn + ni * 16 + l16;
        float v = acc[mi][ni][r];
        if (BIAS) v += bias[col];
        const size_t idx = (size_t)row * N + col;
        if (RES)  v += (float)resid[idx];
        if (RELU) v = fmaxf(v, 0.f);
        if (OUTB) Cb[idx] = (bf16)v;
        else      Cf[idx] = v;
      }
    }
  }
}

// ---------------------------------------------------------------------------
// Flash attention, MFMA. One block = (b, h, 64-row q tile), 4 waves x 16 q
// rows. KV tiles of 64, double-buffered + 1-deep prefetch. K/V^T staged via
// global_load_lds (linear dest) with XOR-swizzled global source column;
// ds_read_b128 fragment reads conflict-free. V^T produced by the QKV/KV
// GEMMs: VT [b*8+h][64 dh][512 t]. P per-wave in LDS, same swizzle.
// XCD swizzle: 8 q-tile blocks of one (b,h) colocate -> K/V L2 reuse.
// ---------------------------------------------------------------------------
template<int CAUSAL>
__global__ __launch_bounds__(256, 4) void attn_k(
    const bf16* __restrict__ Q, const bf16* __restrict__ Kg,
    const bf16* __restrict__ VT, bf16* __restrict__ O, int qs, int kvs)
{
  __shared__ __align__(16) bf16 Kl[2][64 * 64];
  __shared__ __align__(16) bf16 Vl[2][64 * 64];
  __shared__ __align__(16) bf16 plb[4 * 16 * 64];
  const int tid = threadIdx.x;
  const int wid = tid >> 6, lane = tid & 63;
  const int g = lane >> 4, l16 = lane & 15;

  // grid (8,8,16) flattened; XCD swizzle (nwg=1024, q=128)
  int lin = blockIdx.x + 8 * blockIdx.y + 64 * blockIdx.z;
  lin = (lin & 7) * 128 + (lin >> 3);
  const int qt = lin & 7, h = (lin >> 3) & 7, b = lin >> 6;

  const int q0 = qt * 64 + wid * 16;
  const size_t tokQ = (size_t)b * 512 + q0;

  const bf16* qp = Q + (tokQ + l16) * (size_t)qs + h * 64 + g * 8;
  const bf16x8 qf0 = *(const bf16x8*)qp;
  const bf16x8 qf1 = *(const bf16x8*)(qp + 32);

  // staging source: row sr = tid>>3, swizzled col (both-sides pattern)
  const int sr = tid >> 3;
  const int cs2 = ((((tid & 7) * 16) ^ ((sr & 7) << 4)) >> 1);  // bf16 elems
  const bf16* Ksrc = Kg + ((size_t)b * 512 + sr) * kvs + h * 64 + cs2;
  const bf16* Vsrc = VT + (size_t)(b * 8 + h) * 64 * 512 + (size_t)sr * 512 + cs2;
  bf16* pw = plb + wid * 1024;

  auto stage = [&](int sel, int t0) {
    GL16(Ksrc + (size_t)t0 * kvs, &Kl[sel][tid * 8]);
    GL16(Ksrc + (size_t)(t0 + 32) * kvs, &Kl[sel][tid * 8 + 2048]);
    GL16(Vsrc + t0, &Vl[sel][tid * 8]);
    GL16(Vsrc + 32 * 512 + t0, &Vl[sel][tid * 8 + 2048]);
  };

  const f32x4 z4 = {0.f, 0.f, 0.f, 0.f};
  float m[4], ls[4];
  f32x4 o[4];
#pragma unroll
  for (int r = 0; r < 4; ++r) { m[r] = -1e30f; ls[r] = 0.f; o[r] = z4; }

  const int sw = (l16 & 7) << 4;   // byte swizzle for fragment reads
  const int ktmax = CAUSAL ? qt : 7;
  stage(0, 0);
  int cur = 0;
  for (int kt = 0; kt <= ktmax; ++kt) {
    const int t0 = kt * 64;
    __builtin_amdgcn_sched_barrier(0);
    asm volatile("s_waitcnt vmcnt(0)" ::: "memory");
    __builtin_amdgcn_s_barrier();
    if (kt < ktmax) stage(cur ^ 1, t0 + 64);    // prefetch next KV tile

    // QK^T -> 4 16x16 tiles per wave (t cols t0 + jt*16 + l16)
    f32x4 sc[4];
#pragma unroll
    for (int jt = 0; jt < 4; ++jt) {
      const int rk = jt * 16 + l16;
      const bf16x8 kf0 = *(const bf16x8*)&Kl[cur][rk * 64 + (((g * 16) ^ sw) >> 1)];
      const bf16x8 kf1 = *(const bf16x8*)&Kl[cur][rk * 64 + (((g * 16 + 64) ^ sw) >> 1)];
      sc[jt] = mfma16(qf0, kf0, z4);
      sc[jt] = mfma16(qf1, kf1, sc[jt]);
    }
    // online softmax per row r (row q = g*4+r, col = jt*16+l16)
#pragma unroll
    for (int r = 0; r < 4; ++r) {
      const int q = g * 4 + r;
      const int srow = q0 + q;
      const int qs7 = (q & 7) << 4;
      float pv[4];
      float mx = -1e30f;
#pragma unroll
      for (int jt = 0; jt < 4; ++jt) {
        float v = sc[jt][r] * 0.125f;   // 1/sqrt(64)
        if (CAUSAL && (t0 + jt * 16 + l16) > srow) v = -1e30f;
        pv[jt] = v;
        mx = fmaxf(mx, v);
      }
#pragma unroll
      for (int msk = 8; msk; msk >>= 1) mx = fmaxf(mx, __shfl_xor(mx, msk));
      const float mn = fmaxf(m[r], mx);
      const float corr = __expf(m[r] - mn);
      float s = 0.f;
#pragma unroll
      for (int jt = 0; jt < 4; ++jt) {
        const float p = __expf(pv[jt] - mn);
        s += p;
        const int sb = (((jt * 16 + l16) * 2) ^ qs7) >> 1;
        pw[q * 64 + sb] = (bf16)p;
      }
#pragma unroll
      for (int msk = 8; msk; msk >>= 1) s += __shfl_xor(s, msk);
      ls[r] = ls[r] * corr + s;
      m[r] = mn;
#pragma unroll
      for (int j = 0; j < 4; ++j) o[j][r] *= corr;
    }
    // same-wave LDS visibility for P (no cross-wave sharing of P)
    asm volatile("s_waitcnt lgkmcnt(0)" ::: "memory");
    __builtin_amdgcn_sched_barrier(0);
    const bf16x8 pa0 = *(const bf16x8*)&pw[l16 * 64 + (((g * 16) ^ sw) >> 1)];
    const bf16x8 pa1 = *(const bf16x8*)&pw[l16 * 64 + (((g * 16 + 64) ^ sw) >> 1)];
#pragma unroll
    for (int j = 0; j < 4; ++j) {
      const int rv = j * 16 + l16;
      const bf16x8 vf0 = *(const bf16x8*)&Vl[cur][rv * 64 + (((g * 16) ^ sw) >> 1)];
      const bf16x8 vf1 = *(const bf16x8*)&Vl[cur][rv * 64 + (((g * 16 + 64) ^ sw) >> 1)];
      o[j] = mfma16(pa0, vf0, o[j]);
      o[j] = mfma16(pa1, vf1, o[j]);
    }
    cur ^= 1;
  }
#pragma unroll
  for (int r = 0; r < 4; ++r) {
    const float inv = 1.f / ls[r];
    bf16* op = O + (tokQ + g * 4 + r) * 512 + h * 64;
#pragma unroll
    for (int j = 0; j < 4; ++j) op[j * 16 + l16] = (bf16)(o[j][r] * inv);
  }
}

// ---------------------------------------------------------------------------
// LayerNorm over D=512. One wave per row; fp32 math; writes bf16 and/or fp32.
// ---------------------------------------------------------------------------
__global__ __launch_bounds__(256) void ln_k(
    const float* __restrict__ z, const float* __restrict__ gam,
    const float* __restrict__ bet, float* __restrict__ of,
    bf16* __restrict__ ob)
{
  const int wid = threadIdx.x >> 6, lane = threadIdx.x & 63;
  const int row = blockIdx.x * 4 + wid;
  const f32x4* zr = (const f32x4*)(z + (size_t)row * 512);
  const f32x4 a = zr[lane], c = zr[lane + 64];
  float s = 0.f, ss = 0.f;
#pragma unroll
  for (int e = 0; e < 4; ++e) {
    s += a[e] + c[e];
    ss += a[e] * a[e] + c[e] * c[e];
  }
#pragma unroll
  for (int msk = 32; msk; msk >>= 1) {
    s += __shfl_xor(s, msk);
    ss += __shfl_xor(ss, msk);
  }
  const float mean = s * (1.f / 512.f);
  const float var = ss * (1.f / 512.f) - mean * mean;
  const float rstd = rsqrtf(var + 1e-5f);
  const f32x4* gp = (const f32x4*)gam;
  const f32x4* bp = (const f32x4*)bet;
  const f32x4 g0 = gp[lane], g1 = gp[lane + 64];
  const f32x4 b0 = bp[lane], b1 = bp[lane + 64];
  f32x4 o0, o1;
#pragma unroll
  for (int e = 0; e < 4; ++e) {
    o0[e] = (a[e] - mean) * rstd * g0[e] + b0[e];
    o1[e] = (c[e] - mean) * rstd * g1[e] + b1[e];
  }
  if (of) {
    f32x4* ofr = (f32x4*)(of + (size_t)row * 512);
    ofr[lane] = o0;
    ofr[lane + 64] = o1;
  }
  if (ob) {
    bf16x4 c0, c1;
#pragma unroll
    for (int e = 0; e < 4; ++e) { c0[e] = (bf16)o0[e]; c1[e] = (bf16)o1[e]; }
    bf16x4* obr = (bf16x4*)(ob + (size_t)row * 512);
    obr[lane] = c0;
    obr[lane + 64] = c1;
  }
}

// ---------------------------------------------------------------------------
// Tiled transpose + fp32->bf16 cast: per batch z, src [R][C] -> dst [C][R].
// ---------------------------------------------------------------------------
__global__ void transpose_cast(const float* __restrict__ src, bf16* __restrict__ dst,
                               int R, int C, int bpl, size_t lstride, size_t boff)
{
  __shared__ float t[32][33];
  const int z = blockIdx.z;
  src += (size_t)z * R * C;
  dst += (size_t)(z / bpl) * lstride + (size_t)(z % bpl) * ((size_t)R * C) + boff;
  const int c0 = blockIdx.x * 32, r0 = blockIdx.y * 32;
  const int tx = threadIdx.x, ty = threadIdx.y;   // (32, 8)
#pragma unroll
  for (int j = 0; j < 32; j += 8)
    t[ty + j][tx] = src[(size_t)(r0 + ty + j) * C + c0 + tx];
  __syncthreads();
#pragma unroll
  for (int j = 0; j < 32; j += 8)
    dst[(size_t)(c0 + ty + j) * R + r0 + tx] = (bf16)t[tx][ty + j];
}

__global__ void cast4(const float* __restrict__ s, bf16* __restrict__ d)
{
  const int i = blockIdx.x * 256 + threadIdx.x;
  const f32x4 v = ((const f32x4*)s)[i];
  bf16x4 c;
#pragma unroll
  for (int e = 0; e < 4; ++e) c[e] = (bf16)v[e];
  ((bf16x4*)d)[i] = c;
}

// ---------------------------------------------------------------------------
extern "C" void kernel_launch(void* const* d_in, const int* in_sizes, int n_in,
                              void* d_out, int out_size, void* d_ws, size_t ws_size,
                              hipStream_t stream)
{
  (void)in_sizes; (void)n_in; (void)out_size; (void)ws_size;
  const float* x   = (const float*)d_in[0];
  const float* y   = (const float*)d_in[1];
  const float* Wq1 = (const float*)d_in[2];
  const float* Wk1 = (const float*)d_in[3];
  const float* Wv1 = (const float*)d_in[4];
  const float* Wo1 = (const float*)d_in[5];
  const float* Wq2 = (const float*)d_in[6];
  const float* Wk2 = (const float*)d_in[7];
  const float* Wv2 = (const float*)d_in[8];
  const float* Wo2 = (const float*)d_in[9];
  const float* W1  = (const float*)d_in[10];
  const float* b1  = (const float*)d_in[11];
  const float* W2  = (const float*)d_in[12];
  const float* b2  = (const float*)d_in[13];
  const float* ln1g = (const float*)d_in[14];
  const float* ln1b = (const float*)d_in[15];
  const float* ln2g = (const float*)d_in[16];
  const float* ln2b = (const float*)d_in[17];
  const float* ln3g = (const float*)d_in[18];
  const float* ln3b = (const float*)d_in[19];

  char* ws = (char*)d_ws;
  size_t off = 0;
  auto alloc = [&](size_t bytes) -> void* {
    void* p = (void*)(ws + off);
    off += (bytes + 255) & ~(size_t)255;
    return p;
  };

  // weights (bf16, [N][K] transposed)
  bf16* wqkv1t = (bf16*)alloc((size_t)6 * 1536 * 512 * 2);
  bf16* wo1t   = (bf16*)alloc((size_t)6 * 512 * 512 * 2);
  bf16* wq2t   = (bf16*)alloc((size_t)6 * 512 * 512 * 2);
  bf16* wk2t   = (bf16*)alloc((size_t)6 * 512 * 512 * 2);
  bf16* wv2t   = (bf16*)alloc((size_t)6 * 512 * 512 * 2);
  bf16* wo2t   = (bf16*)alloc((size_t)6 * 512 * 512 * 2);
  bf16* w1t    = (bf16*)alloc((size_t)6 * 512 * 2048 * 2);
  bf16* w2t    = (bf16*)alloc((size_t)6 * 2048 * 512 * 2);
  // activations
  bf16* xb   = (bf16*)alloc((size_t)8192 * 512 * 2);
  bf16* yb   = (bf16*)alloc((size_t)8192 * 512 * 2);
  bf16* qkvb = (bf16*)alloc((size_t)8192 * 1536 * 2);
  bf16* qb   = (bf16*)alloc((size_t)8192 * 512 * 2);   // contiguous after qkvb
  bf16* ab   = (bf16*)alloc((size_t)8192 * 512 * 2);
  bf16* h1b  = (bf16*)alloc((size_t)8192 * 512 * 2);
  bf16* h2b  = (bf16*)alloc((size_t)8192 * 512 * 2);
  float* zf  = (float*)alloc((size_t)8192 * 512 * 4);
  bf16* vt1  = (bf16*)alloc((size_t)8192 * 512 * 2);       // V^T self-attn
  bf16* k2all  = (bf16*)alloc((size_t)8192 * 3072 * 2);    // K cross, 6 layers
  bf16* vt2all = (bf16*)alloc((size_t)6 * 8192 * 512 * 2); // V^T cross, 6 layers
  bf16* f1b  = qkvb;          // aliases qkvb+qb (33.5 MB), both dead during FFN

  // --- weight prep ---
  const dim3 tb(32, 8);
  transpose_cast<<<dim3(2, 16, 48), tb, 0, stream>>>(Wq1, wqkv1t, 512, 64, 8, (size_t)1536 * 512, 0);
  transpose_cast<<<dim3(2, 16, 48), tb, 0, stream>>>(Wk1, wqkv1t, 512, 64, 8, (size_t)1536 * 512, (size_t)512 * 512);
  transpose_cast<<<dim3(2, 16, 48), tb, 0, stream>>>(Wv1, wqkv1t, 512, 64, 8, (size_t)1536 * 512, (size_t)1024 * 512);
  transpose_cast<<<dim3(16, 16, 6), tb, 0, stream>>>(Wo1, wo1t, 512, 512, 1, (size_t)512 * 512, 0);
  transpose_cast<<<dim3(2, 16, 48), tb, 0, stream>>>(Wq2, wq2t, 512, 64, 8, (size_t)512 * 512, 0);
  transpose_cast<<<dim3(2, 16, 48), tb, 0, stream>>>(Wk2, wk2t, 512, 64, 8, (size_t)512 * 512, 0);
  transpose_cast<<<dim3(2, 16, 48), tb, 0, stream>>>(Wv2, wv2t, 512, 64, 8, (size_t)512 * 512, 0);
  transpose_cast<<<dim3(16, 16, 6), tb, 0, stream>>>(Wo2, wo2t, 512, 512, 1, (size_t)512 * 512, 0);
  transpose_cast<<<dim3(64, 16, 6), tb, 0, stream>>>(W1, w1t, 512, 2048, 1, (size_t)512 * 2048, 0);
  transpose_cast<<<dim3(16, 64, 6), tb, 0, stream>>>(W2, w2t, 2048, 512, 1, (size_t)2048 * 512, 0);
  cast4<<<4096, 256, 0, stream>>>(x, xb);
  cast4<<<4096, 256, 0, stream>>>(y, yb);

  const dim3 g512s(8, 64), g1536(12, 64), gff(16, 64), g3072(24, 64);

  // --- hoisted cross-attn K/V projections (depend only on y; all 6 layers) ---
  // K: k2all[t][l*512 + h*64 + dh], N=3072
  gemm_k<128, 0, 0, 0, 1, 0><<<g3072, 256, 0, stream>>>(yb, wk2t, nullptr, k2all,
                                                        nullptr, nullptr, nullptr, 0, 8192, 3072, 512);
  // V: transposed write -> vt2all[l][b*8+h][dh][t], N=3072, all blocks VTO
  gemm_k<128, 0, 0, 0, 1, 1><<<g3072, 256, 0, stream>>>(yb, wv2t, nullptr, nullptr,
                                                        nullptr, nullptr, vt2all, 0, 8192, 3072, 512);

  const bf16* curxb = xb;
  for (int l = 0; l < 6; ++l) {
    const bf16* WQKV1 = wqkv1t + (size_t)l * 1536 * 512;
    const bf16* WO1   = wo1t   + (size_t)l * 512 * 512;
    const bf16* WQ2   = wq2t   + (size_t)l * 512 * 512;
    const bf16* WO2   = wo2t   + (size_t)l * 512 * 512;
    const bf16* W1T   = w1t    + (size_t)l * 2048 * 512;
    const bf16* W2T   = w2t    + (size_t)l * 512 * 2048;

    // masked self-attention + residual + LN1 (QKV gemm writes V^T directly)
    gemm_k<128, 0, 0, 0, 1, 1><<<g1536, 256, 0, stream>>>(curxb, WQKV1, nullptr, qkvb,
                                                          nullptr, nullptr, vt1, 1024, 8192, 1536, 512);
    attn_k<1><<<dim3(8, 8, 16), 256, 0, stream>>>(qkvb, qkvb + 512, vt1, ab, 1536, 1536);
    gemm_k<64, 0, 0, 1, 0, 0><<<g512s, 256, 0, stream>>>(ab, WO1, zf, nullptr,
                                                         nullptr, curxb, nullptr, 0, 8192, 512, 512);
    ln_k<<<2048, 256, 0, stream>>>(zf, ln1g + l * 512, ln1b + l * 512, nullptr, h1b);

    // cross-attention + residual + LN2 (K/V^T precomputed above)
    gemm_k<64, 0, 0, 0, 1, 0><<<g512s, 256, 0, stream>>>(h1b, WQ2, nullptr, qb,
                                                         nullptr, nullptr, nullptr, 0, 8192, 512, 512);
    attn_k<0><<<dim3(8, 8, 16), 256, 0, stream>>>(qb, k2all + (size_t)l * 512,
                                                  vt2all + (size_t)l * 8192 * 512, ab, 512, 3072);
    gemm_k<64, 0, 0, 1, 0, 0><<<g512s, 256, 0, stream>>>(ab, WO2, zf, nullptr,
                                                         nullptr, h1b, nullptr, 0, 8192, 512, 512);
    ln_k<<<2048, 256, 0, stream>>>(zf, ln2g + l * 512, ln2b + l * 512, nullptr, h2b);

    // FFN + residual + LN3
    gemm_k<128, 1, 1, 0, 1, 0><<<gff, 256, 0, stream>>>(h2b, W1T, nullptr, f1b,
                                                        b1 + l * 2048, nullptr, nullptr, 0, 8192, 2048, 512);
    gemm_k<64, 0, 1, 1, 0, 0><<<g512s, 256, 0, stream>>>(f1b, W2T, zf, nullptr,
                                                         b2 + l * 512, h2b, nullptr, 0, 8192, 512, 2048);
    float* outf = (l == 5) ? (float*)d_out : nullptr;
    bf16* outb  = (l == 5) ? nullptr : xb;
    ln_k<<<2048, 256, 0, stream>>>(zf, ln3g + l * 512, ln3b + l * 512, outf, outb);
    curxb = xb;
  }
}

// Round 11
// 1144.451 us; speedup vs baseline: 1.2384x; 1.1090x over previous
//
#include <hip/hip_runtime.h>

typedef __bf16 bf16;
typedef __attribute__((ext_vector_type(8))) __bf16 bf16x8;
typedef __attribute__((ext_vector_type(4))) __bf16 bf16x4;
typedef __attribute__((ext_vector_type(4))) float f32x4;

#define GL16(gp, lp) __builtin_amdgcn_global_load_lds( \
    (const __attribute__((address_space(1))) unsigned int*)(gp), \
    (__attribute__((address_space(3))) unsigned int*)(lp), 16, 0, 0)

__device__ __forceinline__ f32x4 mfma16(bf16x8 a, bf16x8 b, f32x4 c) {
  return __builtin_amdgcn_mfma_f32_16x16x32_bf16(a, b, c, 0, 0, 0);
}

// ---------------------------------------------------------------------------
// Generic bf16 GEMM: C[M][N] = A[M][K] (bf16, row-major) * Bt[N][K]^T (bf16)
// BM=128 x BN tile, BK=64, 2 LDS buffers, m97 order: vmcnt(0); barrier;
// stage(next); compute. Byte-XOR swizzle both sides -> <=2-way LDS banks.
// XCD-aware block swizzle. ldc = C/resid row stride (may differ from N).
// Optional: bias (fp32), residual (bf16), ReLU, bf16/fp32 out. VTO: blocks
// with bn >= vtc0 write output TRANSPOSED into vt[l][b*8+h][dh 64][t 512]
// (gdh = col-vtc0, l=gdh>>9, h=(gdh>>6)&7) -- staged through LDS so the
// global stores are 16B chunks of contiguous 256B t-rows (no partial-line RMW).
// ---------------------------------------------------------------------------
template<int BN, int RELU, int BIAS, int RES, int OUTB, int VTO>
__global__ __launch_bounds__(256, (BN == 64) ? 3 : 2) void gemm_k(
    const bf16* __restrict__ A, const bf16* __restrict__ Bt,
    float* __restrict__ Cf, bf16* __restrict__ Cb,
    const float* __restrict__ bias, const bf16* __restrict__ resid,
    bf16* __restrict__ vt, int vtc0,
    int M, int N, int ldc, int K)
{
  constexpr int MI = 4;
  constexpr int NI = BN / 32;
  __shared__ __align__(16) bf16 smem[(2 * 128 + 2 * BN) * 64];
  bf16* Al0 = smem;                   // [2][128*64]
  bf16* Bl0 = smem + 2 * 128 * 64;    // [2][BN*64]
  const int tid = threadIdx.x;
  const int wid = tid >> 6, lane = tid & 63;
  const int g = lane >> 4, l16 = lane & 15;

  // XCD swizzle: HW assigns XCD = lin%8; give each XCD a contiguous tile range
  int lin = blockIdx.x + gridDim.x * blockIdx.y;
  const int nwg = gridDim.x * gridDim.y;
  if ((nwg & 7) == 0) lin = (lin & 7) * (nwg >> 3) + (lin >> 3);
  const int bx = lin % gridDim.x, by = lin / gridDim.x;

  const int bm = by * 128, bn = bx * BN;
  const int wm = (wid >> 1) * 64;
  const int wn = (wid & 1) * (BN / 2);

  const f32x4 z4 = {0.f, 0.f, 0.f, 0.f};
  f32x4 acc[MI][NI];
#pragma unroll
  for (int i = 0; i < MI; ++i)
#pragma unroll
    for (int j = 0; j < NI; ++j) acc[i][j] = z4;

  // staging: sweep covers 32 rows x 64 cols (4KB). sr = tid>>3 (0..31),
  // source col byte pre-swizzled with ^((sr&7)<<4).
  const int sr = tid >> 3;
  const int scs = ((((tid & 7) * 16) ^ ((sr & 7) << 4)) >> 1);  // elems
  const bf16* Ag = A + (size_t)(bm + sr) * K + scs;
  const bf16* Bg = Bt + (size_t)(bn + sr) * K + scs;
  const size_t kstep32 = (size_t)32 * K;

  auto stage = [&](int sel, int k0) {
#pragma unroll
    for (int sw = 0; sw < 4; ++sw)
      GL16(Ag + k0 + sw * kstep32, &Al0[sel * 8192 + sw * 2048 + tid * 8]);
#pragma unroll
    for (int sw = 0; sw < BN / 32; ++sw)
      GL16(Bg + k0 + sw * kstep32, &Bl0[sel * (BN * 64) + sw * 2048 + tid * 8]);
  };

  const int nsteps = K >> 6;
  stage(0, 0);
  int cur = 0;
  for (int s = 0; s < nsteps; ++s) {
    __builtin_amdgcn_sched_barrier(0);
    asm volatile("s_waitcnt vmcnt(0)" ::: "memory");
    __builtin_amdgcn_s_barrier();
    __builtin_amdgcn_sched_barrier(0);
    if (s + 1 < nsteps) stage(cur ^ 1, (s + 1) * 64);  // prefetch next K-step
    bf16x8 af[MI][2], bfr[NI][2];
#pragma unroll
    for (int mi = 0; mi < MI; ++mi) {
      const int row = wm + mi * 16 + l16;
      const int rs = (row & 7) << 4;
#pragma unroll
      for (int kh = 0; kh < 2; ++kh)
        af[mi][kh] = *(const bf16x8*)&Al0[cur * 8192 + row * 64 + (((g * 16 + kh * 64) ^ rs) >> 1)];
    }
#pragma unroll
    for (int ni = 0; ni < NI; ++ni) {
      const int row = wn + ni * 16 + l16;
      const int rs = (row & 7) << 4;
#pragma unroll
      for (int kh = 0; kh < 2; ++kh)
        bfr[ni][kh] = *(const bf16x8*)&Bl0[cur * (BN * 64) + row * 64 + (((g * 16 + kh * 64) ^ rs) >> 1)];
    }
#pragma unroll
    for (int kh = 0; kh < 2; ++kh)
#pragma unroll
      for (int mi = 0; mi < MI; ++mi)
#pragma unroll
        for (int ni = 0; ni < NI; ++ni)
          acc[mi][ni] = mfma16(af[mi][kh], bfr[ni][kh], acc[mi][ni]);
    cur ^= 1;
  }

  if (VTO && bn >= vtc0) {
    // coalesced transposed write: stage [dh][t] tile in LDS (pad 136), then
    // 16B stores over contiguous 256B t-rows of vt.
    __syncthreads();   // K-loop LDS reads complete in all waves
    bf16* stg = smem;  // BN*136 elems <= smem size
#pragma unroll
    for (int mi = 0; mi < MI; ++mi) {
#pragma unroll
      for (int ni = 0; ni < NI; ++ni) {
        const int dhl = wn + ni * 16 + l16;
        const int t0 = wm + mi * 16 + g * 4;
        bf16x4 v4;
#pragma unroll
        for (int r = 0; r < 4; ++r) v4[r] = (bf16)acc[mi][ni][r];
        *(bf16x4*)&stg[dhl * 136 + t0] = v4;
      }
    }
    __syncthreads();
    const int b0 = bm >> 9, tseg = bm & 511;
#pragma unroll
    for (int it = 0; it < BN / 16; ++it) {
      const int flat = it * 256 + tid;
      const int dhl = flat >> 4;
      const int t8 = (flat & 15) * 8;
      const int gdh = bn + dhl - vtc0;
      const int lL = gdh >> 9, hh = (gdh >> 6) & 7, dh = gdh & 63;
      const bf16x8 v = *(const bf16x8*)&stg[dhl * 136 + t8];
      *(bf16x8*)&vt[(((size_t)lL * 128 + b0 * 8 + hh) * 64 + dh) * 512 + tseg + t8] = v;
    }
    return;
  }

#pragma unroll
  for (int mi = 0; mi < MI; ++mi) {
#pragma unroll
    for (int ni = 0; ni < NI; ++ni) {
#pragma unroll
      for (int r = 0; r < 4; ++r) {
        const int row = bm + wm + mi * 16 + g * 4 + r;
        const int col = bn + wn + ni * 16 + l16;
        float v = acc[mi][ni][r];
        if (BIAS) v += bias[col];
        const size_t idx = (size_t)row * ldc + col;
        if (RES)  v += (float)resid[idx];
        if (RELU) v = fmaxf(v, 0.f);
        if (OUTB) Cb[idx] = (bf16)v;
        else      Cf[idx] = v;
      }
    }
  }
}

// ---------------------------------------------------------------------------
// Flash attention, MFMA. One block = (b, h, 64-row q tile), 4 waves x 16 q
// rows. KV tiles of 64, double-buffered + 1-deep prefetch. K/V^T staged via
// global_load_lds (linear dest) with XOR-swizzled global source column;
// ds_read_b128 fragment reads conflict-free. V^T produced by the GEMMs:
// VT [b*8+h][64 dh][512 t]. P per-wave in LDS, same swizzle.
// ---------------------------------------------------------------------------
template<int CAUSAL>
__global__ __launch_bounds__(256, 4) void attn_k(
    const bf16* __restrict__ Q, const bf16* __restrict__ Kg,
    const bf16* __restrict__ VT, bf16* __restrict__ O, int qs, int kvs)
{
  __shared__ __align__(16) bf16 Kl[2][64 * 64];
  __shared__ __align__(16) bf16 Vl[2][64 * 64];
  __shared__ __align__(16) bf16 plb[4 * 16 * 64];
  const int tid = threadIdx.x;
  const int wid = tid >> 6, lane = tid & 63;
  const int g = lane >> 4, l16 = lane & 15;

  // grid (8,8,16) flattened; XCD swizzle (nwg=1024, q=128)
  int lin = blockIdx.x + 8 * blockIdx.y + 64 * blockIdx.z;
  lin = (lin & 7) * 128 + (lin >> 3);
  const int qt = lin & 7, h = (lin >> 3) & 7, b = lin >> 6;

  const int q0 = qt * 64 + wid * 16;
  const size_t tokQ = (size_t)b * 512 + q0;

  const bf16* qp = Q + (tokQ + l16) * (size_t)qs + h * 64 + g * 8;
  const bf16x8 qf0 = *(const bf16x8*)qp;
  const bf16x8 qf1 = *(const bf16x8*)(qp + 32);

  // staging source: row sr = tid>>3, swizzled col (both-sides pattern)
  const int sr = tid >> 3;
  const int cs2 = ((((tid & 7) * 16) ^ ((sr & 7) << 4)) >> 1);  // bf16 elems
  const bf16* Ksrc = Kg + ((size_t)b * 512 + sr) * kvs + h * 64 + cs2;
  const bf16* Vsrc = VT + (size_t)(b * 8 + h) * 64 * 512 + (size_t)sr * 512 + cs2;
  bf16* pw = plb + wid * 1024;

  auto stage = [&](int sel, int t0) {
    GL16(Ksrc + (size_t)t0 * kvs, &Kl[sel][tid * 8]);
    GL16(Ksrc + (size_t)(t0 + 32) * kvs, &Kl[sel][tid * 8 + 2048]);
    GL16(Vsrc + t0, &Vl[sel][tid * 8]);
    GL16(Vsrc + 32 * 512 + t0, &Vl[sel][tid * 8 + 2048]);
  };

  const f32x4 z4 = {0.f, 0.f, 0.f, 0.f};
  float m[4], ls[4];
  f32x4 o[4];
#pragma unroll
  for (int r = 0; r < 4; ++r) { m[r] = -1e30f; ls[r] = 0.f; o[r] = z4; }

  const int sw = (l16 & 7) << 4;   // byte swizzle for fragment reads
  const int ktmax = CAUSAL ? qt : 7;
  stage(0, 0);
  int cur = 0;
  for (int kt = 0; kt <= ktmax; ++kt) {
    const int t0 = kt * 64;
    __builtin_amdgcn_sched_barrier(0);
    asm volatile("s_waitcnt vmcnt(0)" ::: "memory");
    __builtin_amdgcn_s_barrier();
    if (kt < ktmax) stage(cur ^ 1, t0 + 64);    // prefetch next KV tile

    // QK^T -> 4 16x16 tiles per wave (t cols t0 + jt*16 + l16)
    f32x4 sc[4];
#pragma unroll
    for (int jt = 0; jt < 4; ++jt) {
      const int rk = jt * 16 + l16;
      const bf16x8 kf0 = *(const bf16x8*)&Kl[cur][rk * 64 + (((g * 16) ^ sw) >> 1)];
      const bf16x8 kf1 = *(const bf16x8*)&Kl[cur][rk * 64 + (((g * 16 + 64) ^ sw) >> 1)];
      sc[jt] = mfma16(qf0, kf0, z4);
      sc[jt] = mfma16(qf1, kf1, sc[jt]);
    }
    // online softmax per row r (row q = g*4+r, col = jt*16+l16)
#pragma unroll
    for (int r = 0; r < 4; ++r) {
      const int q = g * 4 + r;
      const int srow = q0 + q;
      const int qs7 = (q & 7) << 4;
      float pv[4];
      float mx = -1e30f;
#pragma unroll
      for (int jt = 0; jt < 4; ++jt) {
        float v = sc[jt][r] * 0.125f;   // 1/sqrt(64)
        if (CAUSAL && (t0 + jt * 16 + l16) > srow) v = -1e30f;
        pv[jt] = v;
        mx = fmaxf(mx, v);
      }
#pragma unroll
      for (int msk = 8; msk; msk >>= 1) mx = fmaxf(mx, __shfl_xor(mx, msk));
      const float mn = fmaxf(m[r], mx);
      const float corr = __expf(m[r] - mn);
      float s = 0.f;
#pragma unroll
      for (int jt = 0; jt < 4; ++jt) {
        const float p = __expf(pv[jt] - mn);
        s += p;
        const int sb = (((jt * 16 + l16) * 2) ^ qs7) >> 1;
        pw[q * 64 + sb] = (bf16)p;
      }
#pragma unroll
      for (int msk = 8; msk; msk >>= 1) s += __shfl_xor(s, msk);
      ls[r] = ls[r] * corr + s;
      m[r] = mn;
#pragma unroll
      for (int j = 0; j < 4; ++j) o[j][r] *= corr;
    }
    // same-wave LDS visibility for P (no cross-wave sharing of P)
    asm volatile("s_waitcnt lgkmcnt(0)" ::: "memory");
    __builtin_amdgcn_sched_barrier(0);
    const bf16x8 pa0 = *(const bf16x8*)&pw[l16 * 64 + (((g * 16) ^ sw) >> 1)];
    const bf16x8 pa1 = *(const bf16x8*)&pw[l16 * 64 + (((g * 16 + 64) ^ sw) >> 1)];
#pragma unroll
    for (int j = 0; j < 4; ++j) {
      const int rv = j * 16 + l16;
      const bf16x8 vf0 = *(const bf16x8*)&Vl[cur][rv * 64 + (((g * 16) ^ sw) >> 1)];
      const bf16x8 vf1 = *(const bf16x8*)&Vl[cur][rv * 64 + (((g * 16 + 64) ^ sw) >> 1)];
      o[j] = mfma16(pa0, vf0, o[j]);
      o[j] = mfma16(pa1, vf1, o[j]);
    }
    cur ^= 1;
  }
#pragma unroll
  for (int r = 0; r < 4; ++r) {
    const float inv = 1.f / ls[r];
    bf16* op = O + (tokQ + g * 4 + r) * 512 + h * 64;
#pragma unroll
    for (int j = 0; j < 4; ++j) op[j * 16 + l16] = (bf16)(o[j][r] * inv);
  }
}

// ---------------------------------------------------------------------------
// LayerNorm over D=512. One wave per row; fp32 math; writes bf16 and/or fp32.
// ---------------------------------------------------------------------------
__global__ __launch_bounds__(256) void ln_k(
    const float* __restrict__ z, const float* __restrict__ gam,
    const float* __restrict__ bet, float* __restrict__ of,
    bf16* __restrict__ ob)
{
  const int wid = threadIdx.x >> 6, lane = threadIdx.x & 63;
  const int row = blockIdx.x * 4 + wid;
  const f32x4* zr = (const f32x4*)(z + (size_t)row * 512);
  const f32x4 a = zr[lane], c = zr[lane + 64];
  float s = 0.f, ss = 0.f;
#pragma unroll
  for (int e = 0; e < 4; ++e) {
    s += a[e] + c[e];
    ss += a[e] * a[e] + c[e] * c[e];
  }
#pragma unroll
  for (int msk = 32; msk; msk >>= 1) {
    s += __shfl_xor(s, msk);
    ss += __shfl_xor(ss, msk);
  }
  const float mean = s * (1.f / 512.f);
  const float var = ss * (1.f / 512.f) - mean * mean;
  const float rstd = rsqrtf(var + 1e-5f);
  const f32x4* gp = (const f32x4*)gam;
  const f32x4* bp = (const f32x4*)bet;
  const f32x4 g0 = gp[lane], g1 = gp[lane + 64];
  const f32x4 b0 = bp[lane], b1 = bp[lane + 64];
  f32x4 o0, o1;
#pragma unroll
  for (int e = 0; e < 4; ++e) {
    o0[e] = (a[e] - mean) * rstd * g0[e] + b0[e];
    o1[e] = (c[e] - mean) * rstd * g1[e] + b1[e];
  }
  if (of) {
    f32x4* ofr = (f32x4*)(of + (size_t)row * 512);
    ofr[lane] = o0;
    ofr[lane + 64] = o1;
  }
  if (ob) {
    bf16x4 c0, c1;
#pragma unroll
    for (int e = 0; e < 4; ++e) { c0[e] = (bf16)o0[e]; c1[e] = (bf16)o1[e]; }
    bf16x4* obr = (bf16x4*)(ob + (size_t)row * 512);
    obr[lane] = c0;
    obr[lane + 64] = c1;
  }
}

// ---------------------------------------------------------------------------
// Tiled transpose + fp32->bf16 cast: per batch z, src [R][C] -> dst [C][R].
// ---------------------------------------------------------------------------
__global__ void transpose_cast(const float* __restrict__ src, bf16* __restrict__ dst,
                               int R, int C, int bpl, size_t lstride, size_t boff)
{
  __shared__ float t[32][33];
  const int z = blockIdx.z;
  src += (size_t)z * R * C;
  dst += (size_t)(z / bpl) * lstride + (size_t)(z % bpl) * ((size_t)R * C) + boff;
  const int c0 = blockIdx.x * 32, r0 = blockIdx.y * 32;
  const int tx = threadIdx.x, ty = threadIdx.y;   // (32, 8)
#pragma unroll
  for (int j = 0; j < 32; j += 8)
    t[ty + j][tx] = src[(size_t)(r0 + ty + j) * C + c0 + tx];
  __syncthreads();
#pragma unroll
  for (int j = 0; j < 32; j += 8)
    dst[(size_t)(c0 + ty + j) * R + r0 + tx] = (bf16)t[tx][ty + j];
}

__global__ void cast4(const float* __restrict__ s, bf16* __restrict__ d)
{
  const int i = blockIdx.x * 256 + threadIdx.x;
  const f32x4 v = ((const f32x4*)s)[i];
  bf16x4 c;
#pragma unroll
  for (int e = 0; e < 4; ++e) c[e] = (bf16)v[e];
  ((bf16x4*)d)[i] = c;
}

// ---------------------------------------------------------------------------
extern "C" void kernel_launch(void* const* d_in, const int* in_sizes, int n_in,
                              void* d_out, int out_size, void* d_ws, size_t ws_size,
                              hipStream_t stream)
{
  (void)in_sizes; (void)n_in; (void)out_size; (void)ws_size;
  const float* x   = (const float*)d_in[0];
  const float* y   = (const float*)d_in[1];
  const float* Wq1 = (const float*)d_in[2];
  const float* Wk1 = (const float*)d_in[3];
  const float* Wv1 = (const float*)d_in[4];
  const float* Wo1 = (const float*)d_in[5];
  const float* Wq2 = (const float*)d_in[6];
  const float* Wk2 = (const float*)d_in[7];
  const float* Wv2 = (const float*)d_in[8];
  const float* Wo2 = (const float*)d_in[9];
  const float* W1  = (const float*)d_in[10];
  const float* b1  = (const float*)d_in[11];
  const float* W2  = (const float*)d_in[12];
  const float* b2  = (const float*)d_in[13];
  const float* ln1g = (const float*)d_in[14];
  const float* ln1b = (const float*)d_in[15];
  const float* ln2g = (const float*)d_in[16];
  const float* ln2b = (const float*)d_in[17];
  const float* ln3g = (const float*)d_in[18];
  const float* ln3b = (const float*)d_in[19];

  char* ws = (char*)d_ws;
  size_t off = 0;
  auto alloc = [&](size_t bytes) -> void* {
    void* p = (void*)(ws + off);
    off += (bytes + 255) & ~(size_t)255;
    return p;
  };

  // weights (bf16, [N][K] transposed)
  bf16* wqkv1t = (bf16*)alloc((size_t)6 * 1536 * 512 * 2);
  bf16* wo1t   = (bf16*)alloc((size_t)6 * 512 * 512 * 2);
  bf16* wq2t   = (bf16*)alloc((size_t)6 * 512 * 512 * 2);
  bf16* wkv2t  = (bf16*)alloc((size_t)6144 * 512 * 2);   // K rows 0..3071, V rows 3072..6143
  bf16* wo2t   = (bf16*)alloc((size_t)6 * 512 * 512 * 2);
  bf16* w1t    = (bf16*)alloc((size_t)6 * 512 * 2048 * 2);
  bf16* w2t    = (bf16*)alloc((size_t)6 * 2048 * 512 * 2);
  // activations
  bf16* xb   = (bf16*)alloc((size_t)8192 * 512 * 2);
  bf16* yb   = (bf16*)alloc((size_t)8192 * 512 * 2);
  bf16* qkvb = (bf16*)alloc((size_t)8192 * 1536 * 2);
  bf16* qb   = (bf16*)alloc((size_t)8192 * 512 * 2);   // contiguous after qkvb
  bf16* ab   = (bf16*)alloc((size_t)8192 * 512 * 2);
  bf16* h1b  = (bf16*)alloc((size_t)8192 * 512 * 2);
  bf16* h2b  = (bf16*)alloc((size_t)8192 * 512 * 2);
  float* zf  = (float*)alloc((size_t)8192 * 512 * 4);
  bf16* vt1  = (bf16*)alloc((size_t)8192 * 512 * 2);       // V^T self-attn
  bf16* k2all  = (bf16*)alloc((size_t)8192 * 3072 * 2);    // K cross, 6 layers
  bf16* vt2all = (bf16*)alloc((size_t)6 * 8192 * 512 * 2); // V^T cross, 6 layers
  bf16* f1b  = qkvb;          // aliases qkvb+qb (33.5 MB), both dead during FFN

  // --- weight prep ---
  const dim3 tb(32, 8);
  transpose_cast<<<dim3(2, 16, 48), tb, 0, stream>>>(Wq1, wqkv1t, 512, 64, 8, (size_t)1536 * 512, 0);
  transpose_cast<<<dim3(2, 16, 48), tb, 0, stream>>>(Wk1, wqkv1t, 512, 64, 8, (size_t)1536 * 512, (size_t)512 * 512);
  transpose_cast<<<dim3(2, 16, 48), tb, 0, stream>>>(Wv1, wqkv1t, 512, 64, 8, (size_t)1536 * 512, (size_t)1024 * 512);
  transpose_cast<<<dim3(16, 16, 6), tb, 0, stream>>>(Wo1, wo1t, 512, 512, 1, (size_t)512 * 512, 0);
  transpose_cast<<<dim3(2, 16, 48), tb, 0, stream>>>(Wq2, wq2t, 512, 64, 8, (size_t)512 * 512, 0);
  transpose_cast<<<dim3(2, 16, 48), tb, 0, stream>>>(Wk2, wkv2t, 512, 64, 8, (size_t)512 * 512, 0);
  transpose_cast<<<dim3(2, 16, 48), tb, 0, stream>>>(Wv2, wkv2t + (size_t)3072 * 512, 512, 64, 8, (size_t)512 * 512, 0);
  transpose_cast<<<dim3(16, 16, 6), tb, 0, stream>>>(Wo2, wo2t, 512, 512, 1, (size_t)512 * 512, 0);
  transpose_cast<<<dim3(64, 16, 6), tb, 0, stream>>>(W1, w1t, 512, 2048, 1, (size_t)512 * 2048, 0);
  transpose_cast<<<dim3(16, 64, 6), tb, 0, stream>>>(W2, w2t, 2048, 512, 1, (size_t)2048 * 512, 0);
  cast4<<<4096, 256, 0, stream>>>(x, xb);
  cast4<<<4096, 256, 0, stream>>>(y, yb);

  const dim3 g512s(8, 64), g1536(12, 64), gff(16, 64), g6144(48, 64);

  // --- hoisted cross-attn K/V projections (depend only on y; all 6 layers,
  // one dispatch): cols 0..3071 -> k2all (ldc 3072); cols 3072.. -> vt2all.
  gemm_k<128, 0, 0, 0, 1, 1><<<g6144, 256, 0, stream>>>(yb, wkv2t, nullptr, k2all,
                                                        nullptr, nullptr, vt2all, 3072,
                                                        8192, 6144, 3072, 512);

  const bf16* curxb = xb;
  for (int l = 0; l < 6; ++l) {
    const bf16* WQKV1 = wqkv1t + (size_t)l * 1536 * 512;
    const bf16* WO1   = wo1t   + (size_t)l * 512 * 512;
    const bf16* WQ2   = wq2t   + (size_t)l * 512 * 512;
    const bf16* WO2   = wo2t   + (size_t)l * 512 * 512;
    const bf16* W1T   = w1t    + (size_t)l * 2048 * 512;
    const bf16* W2T   = w2t    + (size_t)l * 512 * 2048;

    // masked self-attention + residual + LN1 (QKV gemm writes V^T directly)
    gemm_k<128, 0, 0, 0, 1, 1><<<g1536, 256, 0, stream>>>(curxb, WQKV1, nullptr, qkvb,
                                                          nullptr, nullptr, vt1, 1024,
                                                          8192, 1536, 1536, 512);
    attn_k<1><<<dim3(8, 8, 16), 256, 0, stream>>>(qkvb, qkvb + 512, vt1, ab, 1536, 1536);
    gemm_k<64, 0, 0, 1, 0, 0><<<g512s, 256, 0, stream>>>(ab, WO1, zf, nullptr,
                                                         nullptr, curxb, nullptr, 0,
                                                         8192, 512, 512, 512);
    ln_k<<<2048, 256, 0, stream>>>(zf, ln1g + l * 512, ln1b + l * 512, nullptr, h1b);

    // cross-attention + residual + LN2 (K/V^T precomputed above)
    gemm_k<64, 0, 0, 0, 1, 0><<<g512s, 256, 0, stream>>>(h1b, WQ2, nullptr, qb,
                                                         nullptr, nullptr, nullptr, 0,
                                                         8192, 512, 512, 512);
    attn_k<0><<<dim3(8, 8, 16), 256, 0, stream>>>(qb, k2all + (size_t)l * 512,
                                                  vt2all + (size_t)l * 8192 * 512, ab, 512, 3072);
    gemm_k<64, 0, 0, 1, 0, 0><<<g512s, 256, 0, stream>>>(ab, WO2, zf, nullptr,
                                                         nullptr, h1b, nullptr, 0,
                                                         8192, 512, 512, 512);
    ln_k<<<2048, 256, 0, stream>>>(zf, ln2g + l * 512, ln2b + l * 512, nullptr, h2b);

    // FFN + residual + LN3
    gemm_k<128, 1, 1, 0, 1, 0><<<gff, 256, 0, stream>>>(h2b, W1T, nullptr, f1b,
                                                        b1 + l * 2048, nullptr, nullptr, 0,
                                                        8192, 2048, 2048, 512);
    gemm_k<64, 0, 1, 1, 0, 0><<<g512s, 256, 0, stream>>>(f1b, W2T, zf, nullptr,
                                                         b2 + l * 512, h2b, nullptr, 0,
                                                         8192, 512, 512, 2048);
    float* outf = (l == 5) ? (float*)d_out : nullptr;
    bf16* outb  = (l == 5) ? nullptr : xb;
    ln_k<<<2048, 256, 0, stream>>>(zf, ln3g + l * 512, ln3b + l * 512, outf, outb);
    curxb = xb;
  }
}

// Round 13
// 1131.193 us; speedup vs baseline: 1.2529x; 1.0117x over previous
//
#include <hip/hip_runtime.h>

typedef __bf16 bf16;
typedef __attribute__((ext_vector_type(8))) __bf16 bf16x8;
typedef __attribute__((ext_vector_type(4))) __bf16 bf16x4;
typedef __attribute__((ext_vector_type(4))) float f32x4;

#define GL16(gp, lp) __builtin_amdgcn_global_load_lds( \
    (const __attribute__((address_space(1))) unsigned int*)(gp), \
    (__attribute__((address_space(3))) unsigned int*)(lp), 16, 0, 0)

__device__ __forceinline__ f32x4 mfma16(bf16x8 a, bf16x8 b, f32x4 c) {
  return __builtin_amdgcn_mfma_f32_16x16x32_bf16(a, b, c, 0, 0, 0);
}

// ---------------------------------------------------------------------------
// Generic bf16 GEMM: C[M][N] = A[M][K] (bf16, row-major) * Bt[N][K]^T (bf16)
// BM=128 x BN tile, BK=64, 2 LDS buffers, m97 order: vmcnt(0); barrier;
// stage(next); compute. Byte-XOR swizzle both sides -> <=2-way LDS banks.
// Block order: XCD-chunked; for wide grids (gx>=16) column-major within the
// XCD chunk (concurrent blocks form an 8x8 patch: A-slice hot in L2, B
// streams exactly once per XCD -- fixes B-thrash seen at gx=48: FETCH 165MB).
// ldc = C/resid row stride. Optional bias/resid(bf16)/ReLU, bf16|fp32 out.
// VTO: blocks with bn >= vtc0 write output transposed into
// vt[l][b*8+h][dh 64][t 512], staged through LDS -> coalesced 16B stores.
// ---------------------------------------------------------------------------
template<int BN, int RELU, int BIAS, int RES, int OUTB, int VTO>
__global__ __launch_bounds__(256, (BN == 64) ? 3 : 2) void gemm_k(
    const bf16* __restrict__ A, const bf16* __restrict__ Bt,
    float* __restrict__ Cf, bf16* __restrict__ Cb,
    const float* __restrict__ bias, const bf16* __restrict__ resid,
    bf16* __restrict__ vt, int vtc0,
    int M, int N, int ldc, int K)
{
  constexpr int MI = 4;
  constexpr int NI = BN / 32;
  __shared__ __align__(16) bf16 smem[(2 * 128 + 2 * BN) * 64];
  bf16* Al0 = smem;                   // [2][128*64]
  bf16* Bl0 = smem + 2 * 128 * 64;    // [2][BN*64]
  const int tid = threadIdx.x;
  const int wid = tid >> 6, lane = tid & 63;
  const int g = lane >> 4, l16 = lane & 15;

  const int lin = blockIdx.x + gridDim.x * blockIdx.y;
  const int nwg = gridDim.x * gridDim.y;
  int bx, by;
  if ((nwg & 7) == 0 && gridDim.y == 64 && gridDim.x >= 16) {
    // col-major within XCD chunk: 8x8 patches; B streams once per XCD
    const int xcd = lin & 7, c = lin >> 3;
    by = (xcd << 3) + (c & 7);
    bx = c >> 3;
  } else if ((nwg & 7) == 0) {
    const int l2 = (lin & 7) * (nwg >> 3) + (lin >> 3);
    bx = l2 % gridDim.x; by = l2 / gridDim.x;
  } else {
    bx = lin % gridDim.x; by = lin / gridDim.x;
  }

  const int bm = by * 128, bn = bx * BN;
  const int wm = (wid >> 1) * 64;
  const int wn = (wid & 1) * (BN / 2);

  const f32x4 z4 = {0.f, 0.f, 0.f, 0.f};
  f32x4 acc[MI][NI];
#pragma unroll
  for (int i = 0; i < MI; ++i)
#pragma unroll
    for (int j = 0; j < NI; ++j) acc[i][j] = z4;

  // staging: sweep covers 32 rows x 64 cols (4KB). sr = tid>>3 (0..31),
  // source col byte pre-swizzled with ^((sr&7)<<4).
  const int sr = tid >> 3;
  const int scs = ((((tid & 7) * 16) ^ ((sr & 7) << 4)) >> 1);  // elems
  const bf16* Ag = A + (size_t)(bm + sr) * K + scs;
  const bf16* Bg = Bt + (size_t)(bn + sr) * K + scs;
  const size_t kstep32 = (size_t)32 * K;

  auto stage = [&](int sel, int k0) {
#pragma unroll
    for (int sw = 0; sw < 4; ++sw)
      GL16(Ag + k0 + sw * kstep32, &Al0[sel * 8192 + sw * 2048 + tid * 8]);
#pragma unroll
    for (int sw = 0; sw < BN / 32; ++sw)
      GL16(Bg + k0 + sw * kstep32, &Bl0[sel * (BN * 64) + sw * 2048 + tid * 8]);
  };

  const int nsteps = K >> 6;
  stage(0, 0);
  int cur = 0;
  for (int s = 0; s < nsteps; ++s) {
    __builtin_amdgcn_sched_barrier(0);
    asm volatile("s_waitcnt vmcnt(0)" ::: "memory");
    __builtin_amdgcn_s_barrier();
    __builtin_amdgcn_sched_barrier(0);
    if (s + 1 < nsteps) stage(cur ^ 1, (s + 1) * 64);  // prefetch next K-step
    bf16x8 af[MI][2], bfr[NI][2];
#pragma unroll
    for (int mi = 0; mi < MI; ++mi) {
      const int row = wm + mi * 16 + l16;
      const int rs = (row & 7) << 4;
#pragma unroll
      for (int kh = 0; kh < 2; ++kh)
        af[mi][kh] = *(const bf16x8*)&Al0[cur * 8192 + row * 64 + (((g * 16 + kh * 64) ^ rs) >> 1)];
    }
#pragma unroll
    for (int ni = 0; ni < NI; ++ni) {
      const int row = wn + ni * 16 + l16;
      const int rs = (row & 7) << 4;
#pragma unroll
      for (int kh = 0; kh < 2; ++kh)
        bfr[ni][kh] = *(const bf16x8*)&Bl0[cur * (BN * 64) + row * 64 + (((g * 16 + kh * 64) ^ rs) >> 1)];
    }
#pragma unroll
    for (int kh = 0; kh < 2; ++kh)
#pragma unroll
      for (int mi = 0; mi < MI; ++mi)
#pragma unroll
        for (int ni = 0; ni < NI; ++ni)
          acc[mi][ni] = mfma16(af[mi][kh], bfr[ni][kh], acc[mi][ni]);
    cur ^= 1;
  }

  if (VTO && bn >= vtc0) {
    // coalesced transposed write: stage [dh][t] tile in LDS (pad 136), then
    // 16B stores over contiguous 256B t-rows of vt.
    __syncthreads();   // K-loop LDS reads complete in all waves
    bf16* stg = smem;  // BN*136 elems <= smem size
#pragma unroll
    for (int mi = 0; mi < MI; ++mi) {
#pragma unroll
      for (int ni = 0; ni < NI; ++ni) {
        const int dhl = wn + ni * 16 + l16;
        const int t0 = wm + mi * 16 + g * 4;
        bf16x4 v4;
#pragma unroll
        for (int r = 0; r < 4; ++r) v4[r] = (bf16)acc[mi][ni][r];
        *(bf16x4*)&stg[dhl * 136 + t0] = v4;
      }
    }
    __syncthreads();
    const int b0 = bm >> 9, tseg = bm & 511;
#pragma unroll
    for (int it = 0; it < BN / 16; ++it) {
      const int flat = it * 256 + tid;
      const int dhl = flat >> 4;
      const int t8 = (flat & 15) * 8;
      const int gdh = bn + dhl - vtc0;
      const int lL = gdh >> 9, hh = (gdh >> 6) & 7, dh = gdh & 63;
      const bf16x8 v = *(const bf16x8*)&stg[dhl * 136 + t8];
      *(bf16x8*)&vt[(((size_t)lL * 128 + b0 * 8 + hh) * 64 + dh) * 512 + tseg + t8] = v;
    }
    return;
  }

#pragma unroll
  for (int mi = 0; mi < MI; ++mi) {
#pragma unroll
    for (int ni = 0; ni < NI; ++ni) {
#pragma unroll
      for (int r = 0; r < 4; ++r) {
        const int row = bm + wm + mi * 16 + g * 4 + r;
        const int col = bn + wn + ni * 16 + l16;
        float v = acc[mi][ni][r];
        if (BIAS) v += bias[col];
        const size_t idx = (size_t)row * ldc + col;
        if (RES)  v += (float)resid[idx];
        if (RELU) v = fmaxf(v, 0.f);
        if (OUTB) Cb[idx] = (bf16)v;
        else      Cf[idx] = v;
      }
    }
  }
}

// ---------------------------------------------------------------------------
// Flash attention, MFMA. One block = (b, h, 64-row q tile), 4 waves x 16 q
// rows. KV tiles of 64, double-buffered + 1-deep prefetch. K/V^T staged via
// global_load_lds (linear dest) with XOR-swizzled global source column;
// ds_read_b128 fragment reads conflict-free. V^T produced by the GEMMs:
// VT [b*8+h][64 dh][512 t]. P per-wave in LDS, same swizzle.
// ---------------------------------------------------------------------------
template<int CAUSAL>
__global__ __launch_bounds__(256, 4) void attn_k(
    const bf16* __restrict__ Q, const bf16* __restrict__ Kg,
    const bf16* __restrict__ VT, bf16* __restrict__ O, int qs, int kvs)
{
  __shared__ __align__(16) bf16 Kl[2][64 * 64];
  __shared__ __align__(16) bf16 Vl[2][64 * 64];
  __shared__ __align__(16) bf16 plb[4 * 16 * 64];
  const int tid = threadIdx.x;
  const int wid = tid >> 6, lane = tid & 63;
  const int g = lane >> 4, l16 = lane & 15;

  // grid (8,8,16) flattened; XCD swizzle (nwg=1024, q=128)
  int lin = blockIdx.x + 8 * blockIdx.y + 64 * blockIdx.z;
  lin = (lin & 7) * 128 + (lin >> 3);
  const int qt = lin & 7, h = (lin >> 3) & 7, b = lin >> 6;

  const int q0 = qt * 64 + wid * 16;
  const size_t tokQ = (size_t)b * 512 + q0;

  const bf16* qp = Q + (tokQ + l16) * (size_t)qs + h * 64 + g * 8;
  const bf16x8 qf0 = *(const bf16x8*)qp;
  const bf16x8 qf1 = *(const bf16x8*)(qp + 32);

  // staging source: row sr = tid>>3, swizzled col (both-sides pattern)
  const int sr = tid >> 3;
  const int cs2 = ((((tid & 7) * 16) ^ ((sr & 7) << 4)) >> 1);  // bf16 elems
  const bf16* Ksrc = Kg + ((size_t)b * 512 + sr) * kvs + h * 64 + cs2;
  const bf16* Vsrc = VT + (size_t)(b * 8 + h) * 64 * 512 + (size_t)sr * 512 + cs2;
  bf16* pw = plb + wid * 1024;

  auto stage = [&](int sel, int t0) {
    GL16(Ksrc + (size_t)t0 * kvs, &Kl[sel][tid * 8]);
    GL16(Ksrc + (size_t)(t0 + 32) * kvs, &Kl[sel][tid * 8 + 2048]);
    GL16(Vsrc + t0, &Vl[sel][tid * 8]);
    GL16(Vsrc + 32 * 512 + t0, &Vl[sel][tid * 8 + 2048]);
  };

  const f32x4 z4 = {0.f, 0.f, 0.f, 0.f};
  float m[4], ls[4];
  f32x4 o[4];
#pragma unroll
  for (int r = 0; r < 4; ++r) { m[r] = -1e30f; ls[r] = 0.f; o[r] = z4; }

  const int sw = (l16 & 7) << 4;   // byte swizzle for fragment reads
  const int ktmax = CAUSAL ? qt : 7;
  stage(0, 0);
  int cur = 0;
  for (int kt = 0; kt <= ktmax; ++kt) {
    const int t0 = kt * 64;
    __builtin_amdgcn_sched_barrier(0);
    asm volatile("s_waitcnt vmcnt(0)" ::: "memory");
    __builtin_amdgcn_s_barrier();
    if (kt < ktmax) stage(cur ^ 1, t0 + 64);    // prefetch next KV tile

    // QK^T -> 4 16x16 tiles per wave (t cols t0 + jt*16 + l16)
    f32x4 sc[4];
#pragma unroll
    for (int jt = 0; jt < 4; ++jt) {
      const int rk = jt * 16 + l16;
      const bf16x8 kf0 = *(const bf16x8*)&Kl[cur][rk * 64 + (((g * 16) ^ sw) >> 1)];
      const bf16x8 kf1 = *(const bf16x8*)&Kl[cur][rk * 64 + (((g * 16 + 64) ^ sw) >> 1)];
      sc[jt] = mfma16(qf0, kf0, z4);
      sc[jt] = mfma16(qf1, kf1, sc[jt]);
    }
    // online softmax per row r (row q = g*4+r, col = jt*16+l16)
#pragma unroll
    for (int r = 0; r < 4; ++r) {
      const int q = g * 4 + r;
      const int srow = q0 + q;
      const int qs7 = (q & 7) << 4;
      float pv[4];
      float mx = -1e30f;
#pragma unroll
      for (int jt = 0; jt < 4; ++jt) {
        float v = sc[jt][r] * 0.125f;   // 1/sqrt(64)
        if (CAUSAL && (t0 + jt * 16 + l16) > srow) v = -1e30f;
        pv[jt] = v;
        mx = fmaxf(mx, v);
      }
#pragma unroll
      for (int msk = 8; msk; msk >>= 1) mx = fmaxf(mx, __shfl_xor(mx, msk));
      const float mn = fmaxf(m[r], mx);
      const float corr = __expf(m[r] - mn);
      float s = 0.f;
#pragma unroll
      for (int jt = 0; jt < 4; ++jt) {
        const float p = __expf(pv[jt] - mn);
        s += p;
        const int sb = (((jt * 16 + l16) * 2) ^ qs7) >> 1;
        pw[q * 64 + sb] = (bf16)p;
      }
#pragma unroll
      for (int msk = 8; msk; msk >>= 1) s += __shfl_xor(s, msk);
      ls[r] = ls[r] * corr + s;
      m[r] = mn;
#pragma unroll
      for (int j = 0; j < 4; ++j) o[j][r] *= corr;
    }
    // same-wave LDS visibility for P (no cross-wave sharing of P)
    asm volatile("s_waitcnt lgkmcnt(0)" ::: "memory");
    __builtin_amdgcn_sched_barrier(0);
    const bf16x8 pa0 = *(const bf16x8*)&pw[l16 * 64 + (((g * 16) ^ sw) >> 1)];
    const bf16x8 pa1 = *(const bf16x8*)&pw[l16 * 64 + (((g * 16 + 64) ^ sw) >> 1)];
#pragma unroll
    for (int j = 0; j < 4; ++j) {
      const int rv = j * 16 + l16;
      const bf16x8 vf0 = *(const bf16x8*)&Vl[cur][rv * 64 + (((g * 16) ^ sw) >> 1)];
      const bf16x8 vf1 = *(const bf16x8*)&Vl[cur][rv * 64 + (((g * 16 + 64) ^ sw) >> 1)];
      o[j] = mfma16(pa0, vf0, o[j]);
      o[j] = mfma16(pa1, vf1, o[j]);
    }
    cur ^= 1;
  }
#pragma unroll
  for (int r = 0; r < 4; ++r) {
    const float inv = 1.f / ls[r];
    bf16* op = O + (tokQ + g * 4 + r) * 512 + h * 64;
#pragma unroll
    for (int j = 0; j < 4; ++j) op[j * 16 + l16] = (bf16)(o[j][r] * inv);
  }
}

// ---------------------------------------------------------------------------
// LayerNorm over D=512, fp32 input; fp32 math. One wave per row;
// writes bf16 and/or fp32.
// ---------------------------------------------------------------------------
__global__ __launch_bounds__(256) void ln_k(
    const float* __restrict__ z, const float* __restrict__ gam,
    const float* __restrict__ bet, float* __restrict__ of,
    bf16* __restrict__ ob)
{
  const int wid = threadIdx.x >> 6, lane = threadIdx.x & 63;
  const int row = blockIdx.x * 4 + wid;
  const f32x4* zr = (const f32x4*)(z + (size_t)row * 512);
  const f32x4 a = zr[lane], c = zr[lane + 64];
  float s = 0.f, ss = 0.f;
#pragma unroll
  for (int e = 0; e < 4; ++e) {
    s += a[e] + c[e];
    ss += a[e] * a[e] + c[e] * c[e];
  }
#pragma unroll
  for (int msk = 32; msk; msk >>= 1) {
    s += __shfl_xor(s, msk);
    ss += __shfl_xor(ss, msk);
  }
  const float mean = s * (1.f / 512.f);
  const float var = ss * (1.f / 512.f) - mean * mean;
  const float rstd = rsqrtf(var + 1e-5f);
  const f32x4* gp = (const f32x4*)gam;
  const f32x4* bp = (const f32x4*)bet;
  const f32x4 g0 = gp[lane], g1 = gp[lane + 64];
  const f32x4 b0 = bp[lane], b1 = bp[lane + 64];
  f32x4 o0, o1;
#pragma unroll
  for (int e = 0; e < 4; ++e) {
    o0[e] = (a[e] - mean) * rstd * g0[e] + b0[e];
    o1[e] = (c[e] - mean) * rstd * g1[e] + b1[e];
  }
  if (of) {
    f32x4* ofr = (f32x4*)(of + (size_t)row * 512);
    ofr[lane] = o0;
    ofr[lane + 64] = o1;
  }
  if (ob) {
    bf16x4 c0, c1;
#pragma unroll
    for (int e = 0; e < 4; ++e) { c0[e] = (bf16)o0[e]; c1[e] = (bf16)o1[e]; }
    bf16x4* obr = (bf16x4*)(ob + (size_t)row * 512);
    obr[lane] = c0;
    obr[lane + 64] = c1;
  }
}

// ---------------------------------------------------------------------------
// Tiled transpose + fp32->bf16 cast: per batch z, src [R][C] -> dst [C][R].
// ---------------------------------------------------------------------------
__global__ void transpose_cast(const float* __restrict__ src, bf16* __restrict__ dst,
                               int R, int C, int bpl, size_t lstride, size_t boff)
{
  __shared__ float t[32][33];
  const int z = blockIdx.z;
  src += (size_t)z * R * C;
  dst += (size_t)(z / bpl) * lstride + (size_t)(z % bpl) * ((size_t)R * C) + boff;
  const int c0 = blockIdx.x * 32, r0 = blockIdx.y * 32;
  const int tx = threadIdx.x, ty = threadIdx.y;   // (32, 8)
#pragma unroll
  for (int j = 0; j < 32; j += 8)
    t[ty + j][tx] = src[(size_t)(r0 + ty + j) * C + c0 + tx];
  __syncthreads();
#pragma unroll
  for (int j = 0; j < 32; j += 8)
    dst[(size_t)(c0 + ty + j) * R + r0 + tx] = (bf16)t[tx][ty + j];
}

__global__ void cast4(const float* __restrict__ s, bf16* __restrict__ d)
{
  const int i = blockIdx.x * 256 + threadIdx.x;
  const f32x4 v = ((const f32x4*)s)[i];
  bf16x4 c;
#pragma unroll
  for (int e = 0; e < 4; ++e) c[e] = (bf16)v[e];
  ((bf16x4*)d)[i] = c;
}

// ---------------------------------------------------------------------------
extern "C" void kernel_launch(void* const* d_in, const int* in_sizes, int n_in,
                              void* d_out, int out_size, void* d_ws, size_t ws_size,
                              hipStream_t stream)
{
  (void)in_sizes; (void)n_in; (void)out_size; (void)ws_size;
  const float* x   = (const float*)d_in[0];
  const float* y   = (const float*)d_in[1];
  const float* Wq1 = (const float*)d_in[2];
  const float* Wk1 = (const float*)d_in[3];
  const float* Wv1 = (const float*)d_in[4];
  const float* Wo1 = (const float*)d_in[5];
  const float* Wq2 = (const float*)d_in[6];
  const float* Wk2 = (const float*)d_in[7];
  const float* Wv2 = (const float*)d_in[8];
  const float* Wo2 = (const float*)d_in[9];
  const float* W1  = (const float*)d_in[10];
  const float* b1  = (const float*)d_in[11];
  const float* W2  = (const float*)d_in[12];
  const float* b2  = (const float*)d_in[13];
  const float* ln1g = (const float*)d_in[14];
  const float* ln1b = (const float*)d_in[15];
  const float* ln2g = (const float*)d_in[16];
  const float* ln2b = (const float*)d_in[17];
  const float* ln3g = (const float*)d_in[18];
  const float* ln3b = (const float*)d_in[19];

  char* ws = (char*)d_ws;
  size_t off = 0;
  auto alloc = [&](size_t bytes) -> void* {
    void* p = (void*)(ws + off);
    off += (bytes + 255) & ~(size_t)255;
    return p;
  };

  // weights (bf16, [N][K] transposed)
  bf16* wqkv1t = (bf16*)alloc((size_t)6 * 1536 * 512 * 2);
  bf16* wo1t   = (bf16*)alloc((size_t)6 * 512 * 512 * 2);
  bf16* wq2t   = (bf16*)alloc((size_t)6 * 512 * 512 * 2);
  bf16* wkv2t  = (bf16*)alloc((size_t)6144 * 512 * 2);   // K rows 0..3071, V rows 3072..6143
  bf16* wo2t   = (bf16*)alloc((size_t)6 * 512 * 512 * 2);
  bf16* w1t    = (bf16*)alloc((size_t)6 * 512 * 2048 * 2);
  bf16* w2t    = (bf16*)alloc((size_t)6 * 2048 * 512 * 2);
  // activations
  bf16* xb   = (bf16*)alloc((size_t)8192 * 512 * 2);
  bf16* yb   = (bf16*)alloc((size_t)8192 * 512 * 2);
  bf16* qkvb = (bf16*)alloc((size_t)8192 * 1536 * 2);
  bf16* qb   = (bf16*)alloc((size_t)8192 * 512 * 2);   // contiguous after qkvb
  bf16* ab   = (bf16*)alloc((size_t)8192 * 512 * 2);
  bf16* h1b  = (bf16*)alloc((size_t)8192 * 512 * 2);
  bf16* h2b  = (bf16*)alloc((size_t)8192 * 512 * 2);
  float* zf  = (float*)alloc((size_t)8192 * 512 * 4);
  bf16* vt1  = (bf16*)alloc((size_t)8192 * 512 * 2);       // V^T self-attn
  bf16* k2all  = (bf16*)alloc((size_t)8192 * 3072 * 2);    // K cross, 6 layers
  bf16* vt2all = (bf16*)alloc((size_t)6 * 8192 * 512 * 2); // V^T cross, 6 layers
  bf16* f1b  = qkvb;          // aliases qkvb+qb (33.5 MB), both dead during FFN

  // --- weight prep ---
  const dim3 tb(32, 8);
  transpose_cast<<<dim3(2, 16, 48), tb, 0, stream>>>(Wq1, wqkv1t, 512, 64, 8, (size_t)1536 * 512, 0);
  transpose_cast<<<dim3(2, 16, 48), tb, 0, stream>>>(Wk1, wqkv1t, 512, 64, 8, (size_t)1536 * 512, (size_t)512 * 512);
  transpose_cast<<<dim3(2, 16, 48), tb, 0, stream>>>(Wv1, wqkv1t, 512, 64, 8, (size_t)1536 * 512, (size_t)1024 * 512);
  transpose_cast<<<dim3(16, 16, 6), tb, 0, stream>>>(Wo1, wo1t, 512, 512, 1, (size_t)512 * 512, 0);
  transpose_cast<<<dim3(2, 16, 48), tb, 0, stream>>>(Wq2, wq2t, 512, 64, 8, (size_t)512 * 512, 0);
  transpose_cast<<<dim3(2, 16, 48), tb, 0, stream>>>(Wk2, wkv2t, 512, 64, 8, (size_t)512 * 512, 0);
  transpose_cast<<<dim3(2, 16, 48), tb, 0, stream>>>(Wv2, wkv2t + (size_t)3072 * 512, 512, 64, 8, (size_t)512 * 512, 0);
  transpose_cast<<<dim3(16, 16, 6), tb, 0, stream>>>(Wo2, wo2t, 512, 512, 1, (size_t)512 * 512, 0);
  transpose_cast<<<dim3(64, 16, 6), tb, 0, stream>>>(W1, w1t, 512, 2048, 1, (size_t)512 * 2048, 0);
  transpose_cast<<<dim3(16, 64, 6), tb, 0, stream>>>(W2, w2t, 2048, 512, 1, (size_t)2048 * 512, 0);
  cast4<<<4096, 256, 0, stream>>>(x, xb);
  cast4<<<4096, 256, 0, stream>>>(y, yb);

  const dim3 g512s(8, 64), g1536(12, 64), gff(16, 64), g6144(48, 64);

  // --- hoisted cross-attn K/V projections (depend only on y; all 6 layers,
  // one dispatch): cols 0..3071 -> k2all (ldc 3072); cols 3072.. -> vt2all.
  gemm_k<128, 0, 0, 0, 1, 1><<<g6144, 256, 0, stream>>>(yb, wkv2t, nullptr, k2all,
                                                        nullptr, nullptr, vt2all, 3072,
                                                        8192, 6144, 3072, 512);

  const bf16* curxb = xb;
  for (int l = 0; l < 6; ++l) {
    const bf16* WQKV1 = wqkv1t + (size_t)l * 1536 * 512;
    const bf16* WO1   = wo1t   + (size_t)l * 512 * 512;
    const bf16* WQ2   = wq2t   + (size_t)l * 512 * 512;
    const bf16* WO2   = wo2t   + (size_t)l * 512 * 512;
    const bf16* W1T   = w1t    + (size_t)l * 2048 * 512;
    const bf16* W2T   = w2t    + (size_t)l * 512 * 2048;

    // masked self-attention + residual + LN1 (QKV gemm writes V^T directly)
    gemm_k<128, 0, 0, 0, 1, 1><<<g1536, 256, 0, stream>>>(curxb, WQKV1, nullptr, qkvb,
                                                          nullptr, nullptr, vt1, 1024,
                                                          8192, 1536, 1536, 512);
    attn_k<1><<<dim3(8, 8, 16), 256, 0, stream>>>(qkvb, qkvb + 512, vt1, ab, 1536, 1536);
    gemm_k<64, 0, 0, 1, 0, 0><<<g512s, 256, 0, stream>>>(ab, WO1, zf, nullptr,
                                                         nullptr, curxb, nullptr, 0,
                                                         8192, 512, 512, 512);
    ln_k<<<2048, 256, 0, stream>>>(zf, ln1g + l * 512, ln1b + l * 512, nullptr, h1b);

    // cross-attention + residual + LN2 (K/V^T precomputed above)
    gemm_k<64, 0, 0, 0, 1, 0><<<g512s, 256, 0, stream>>>(h1b, WQ2, nullptr, qb,
                                                         nullptr, nullptr, nullptr, 0,
                                                         8192, 512, 512, 512);
    attn_k<0><<<dim3(8, 8, 16), 256, 0, stream>>>(qb, k2all + (size_t)l * 512,
                                                  vt2all + (size_t)l * 8192 * 512, ab, 512, 3072);
    gemm_k<64, 0, 0, 1, 0, 0><<<g512s, 256, 0, stream>>>(ab, WO2, zf, nullptr,
                                                         nullptr, h1b, nullptr, 0,
                                                         8192, 512, 512, 512);
    ln_k<<<2048, 256, 0, stream>>>(zf, ln2g + l * 512, ln2b + l * 512, nullptr, h2b);

    // FFN + residual + LN3
    gemm_k<128, 1, 1, 0, 1, 0><<<gff, 256, 0, stream>>>(h2b, W1T, nullptr, f1b,
                                                        b1 + l * 2048, nullptr, nullptr, 0,
                                                        8192, 2048, 2048, 512);
    gemm_k<64, 0, 1, 1, 0, 0><<<g512s, 256, 0, stream>>>(f1b, W2T, zf, nullptr,
                                                         b2 + l * 512, h2b, nullptr, 0,
                                                         8192, 512, 512, 2048);
    float* outf = (l == 5) ? (float*)d_out : nullptr;
    bf16* outb  = (l == 5) ? nullptr : xb;
    ln_k<<<2048, 256, 0, stream>>>(zf, ln3g + l * 512, ln3b + l * 512, outf, outb);
    curxb = xb;
  }
}